// Round 20
// baseline (1483.400 us; speedup 1.0000x reference)
//
#include <hip/hip_runtime.h>

// Swin block (all-fp8 GEMMs + fp8 qkv edge): LN1(fp8) -> qkv fp8 GEMM(fp8 out)
//   -> MFMA attn (fp8 QK^T, bf16 PV, fp8 out) -> proj fp8 GEMM(bf16 out)
//   -> scatter+res+LN2(fp8 h2) -> fc1 fp8(+rcp-GELU, fp8 out) -> fc2 fp8(+residual)
// B=64, H=W=56, C=384, WS=7, SS=3, NH=12, hd=32, N=49, nW=64, B_=4096, M=200704
// R20: fp8 GEMM BK 64 -> 128 (fc2 is round-trip-bound: 24 steps x stage/drain/barrier,
//      hbm_bytes already at mandatory floor). LDS 24->48 KB still 2 blocks/CU (fp8!
//      -- m132's bf16 BK=128 regression was the 64KB occupancy cliff, absent here).
//      Barriers halved. Swizzle: LDS chunk s of row r holds global chunk s^((r>>1)&3)
//      (low-2-bit XOR within each 64B half-row); source chunk (lane&7)^((lane>>4)&3)
//      invariant across issues (row bases multiple of 8). Bank occupancy unchanged.

typedef __bf16 bf16x8 __attribute__((ext_vector_type(8)));
typedef float  f32x4  __attribute__((ext_vector_type(4)));
typedef unsigned short u16x4 __attribute__((ext_vector_type(4)));

__device__ __forceinline__ unsigned short f2bf(float f) {
    unsigned int u = __builtin_bit_cast(unsigned int, f);
    u += 0x7fffu + ((u >> 16) & 1u);   // RNE
    return (unsigned short)(u >> 16);
}
__device__ __forceinline__ float bf2f(unsigned short h) {
    return __builtin_bit_cast(float, (unsigned int)h << 16);
}
__device__ __forceinline__ unsigned char f2fp8(float f) {   // e4m3, RNE (HW)
    return (unsigned char)(__builtin_amdgcn_cvt_pk_fp8_f32(f, f, 0, false) & 0xff);
}

// ---------------- weight transpose + cast: W[K,N] f32 -> Bt[N,K] fp8 e4m3 ----------------
__global__ __launch_bounds__(256) void k_transpose8(const float* __restrict__ W,
                                                    unsigned char* __restrict__ Bt,
                                                    int K, int N) {
    int idx = blockIdx.x * 256 + threadIdx.x;
    if (idx >= N * K) return;
    int n = idx / K, k = idx - n * K;
    Bt[idx] = f2fp8(W[(long)k * N + n]);
}

// ---------------- bias+mask table: tbl[mt][h][i][j], 4*12*64*64 f32 ----------------
__global__ __launch_bounds__(256) void k_btab(const float* __restrict__ rpb,
                                              float* __restrict__ tbl) {
    int idx = blockIdx.x * 256 + threadIdx.x;
    if (idx >= 4 * 12 * 4096) return;
    int j = idx & 63, i = (idx >> 6) & 63;
    int slab = idx >> 12;            // mt*12 + h
    int h = slab % 12, mt = slab / 12;
    float v;
    if (j >= 49)      v = -30000.f;
    else if (i >= 49) v = 0.f;
    else {
        int ith = i / 7, itw = i - ith * 7;
        int jth = j / 7, jtw = j - jth * 7;
        v = rpb[((ith - jth + 6) * 13 + (itw - jtw + 6)) * 12 + h];
        bool m = ((mt & 1) && ((ith < 4) != (jth < 4))) ||
                 ((mt & 2) && ((itw < 4) != (jtw < 4)));
        if (m) v -= 100.f;
    }
    tbl[idx] = v;
}

// ---------------- LN1 + cyclic shift(-3,-3) + window partition -> fp8 ----------------
__global__ __launch_bounds__(256) void k_ln1(const float* __restrict__ x,
                                             const float* __restrict__ g,
                                             const float* __restrict__ bb,
                                             unsigned char* __restrict__ xw8) {
    int wid = threadIdx.x >> 6, lane = threadIdx.x & 63;
    int tok = blockIdx.x * 4 + wid;                 // < 200704
    int t  = tok % 49; int b_ = tok / 49;
    int wi = b_ & 63;  int b  = b_ >> 6;
    int th = t / 7, tw = t - th * 7;
    int hs = (wi >> 3) * 7 + th + 3; if (hs >= 56) hs -= 56;
    int vs = (wi & 7) * 7 + tw + 3;  if (vs >= 56) vs -= 56;
    const float2* row = (const float2*)(x + ((long)b * 3136 + hs * 56 + vs) * 384);
    float2 v[3]; float s = 0.f;
    #pragma unroll
    for (int i = 0; i < 3; ++i) { v[i] = row[lane + 64 * i]; s += v[i].x + v[i].y; }
    #pragma unroll
    for (int o = 32; o; o >>= 1) s += __shfl_xor(s, o);
    float mean = s * (1.f / 384.f);
    float q = 0.f;
    #pragma unroll
    for (int i = 0; i < 3; ++i) {
        float dx = v[i].x - mean, dy = v[i].y - mean; q += dx * dx + dy * dy;
    }
    #pragma unroll
    for (int o = 32; o; o >>= 1) q += __shfl_xor(q, o);
    float inv = rsqrtf(q * (1.f / 384.f) + 1e-5f);
    unsigned char* orow = xw8 + (long)tok * 384;
    #pragma unroll
    for (int i = 0; i < 3; ++i) {
        int c = i * 128 + lane * 2;
        unsigned short p = (unsigned short)f2fp8((v[i].x - mean) * inv * g[c] + bb[c])
                         | ((unsigned short)f2fp8((v[i].y - mean) * inv * g[c + 1] + bb[c + 1]) << 8);
        *(unsigned short*)(orow + c) = p;
    }
}

// ------- fused un-roll scatter + residual + LN2: out = x + gather(projout); h2 = LN2(out) fp8 -------
__global__ __launch_bounds__(256) void k_scln(const unsigned short* __restrict__ po,
                                              const float* __restrict__ x,
                                              const float* __restrict__ g,
                                              const float* __restrict__ bb,
                                              float* __restrict__ out,
                                              unsigned char* __restrict__ h2) {
    int wid = threadIdx.x >> 6, lane = threadIdx.x & 63;
    int tok = blockIdx.x * 4 + wid;                 // < 200704
    int b = tok / 3136, rem = tok - b * 3136;
    int hh = rem / 56, ww = rem - hh * 56;
    int u = (hh >= 3) ? hh - 3 : hh + 53;           // inverse roll(+3)
    int v = (ww >= 3) ? ww - 3 : ww + 53;
    int wr = u / 7, th = u - wr * 7;
    int wc = v / 7, tw = v - wc * 7;
    long src = ((long)((b << 6) + wr * 8 + wc) * 49 + th * 7 + tw) * 384;
    const unsigned int* prow = (const unsigned int*)(po + src);    // 2 bf16 / uint
    const float2* xrow = (const float2*)(x + (long)tok * 384);
    float2 o[3]; float s = 0.f;
    #pragma unroll
    for (int i = 0; i < 3; ++i) {
        unsigned int pb = prow[lane + 64 * i];
        float2 xv = xrow[lane + 64 * i];
        o[i].x = xv.x + bf2f((unsigned short)(pb & 0xffffu));
        o[i].y = xv.y + bf2f((unsigned short)(pb >> 16));
        s += o[i].x + o[i].y;
    }
    float2* orow = (float2*)(out + (long)tok * 384);
    #pragma unroll
    for (int i = 0; i < 3; ++i) orow[lane + 64 * i] = o[i];
    #pragma unroll
    for (int of = 32; of; of >>= 1) s += __shfl_xor(s, of);
    float mean = s * (1.f / 384.f);
    float q = 0.f;
    #pragma unroll
    for (int i = 0; i < 3; ++i) {
        float dx = o[i].x - mean, dy = o[i].y - mean; q += dx * dx + dy * dy;
    }
    #pragma unroll
    for (int of = 32; of; of >>= 1) q += __shfl_xor(q, of);
    float inv = rsqrtf(q * (1.f / 384.f) + 1e-5f);
    unsigned char* hrow = h2 + (long)tok * 384;
    #pragma unroll
    for (int i = 0; i < 3; ++i) {
        int c = i * 128 + lane * 2;
        unsigned short p = (unsigned short)f2fp8((o[i].x - mean) * inv * g[c] + bb[c])
                         | ((unsigned short)f2fp8((o[i].y - mean) * inv * g[c + 1] + bb[c + 1]) << 8);
        *(unsigned short*)(hrow + c) = p;
    }
}

// ---------------- MFMA windowed attention: 1 wave = 1 (window, head), 4 waves/block ----------------
// reads fp8 qkv; QK^T via fp8 MFMA; V converted fp8->bf16 at staging (PV bf16 MFMA);
// writes fp8 attn-out (proj GEMM input).
__global__ __launch_bounds__(256) void k_attn(const unsigned char* __restrict__ qkv8,
                                              const float* __restrict__ tbl,     // [4][12][64][64]
                                              unsigned char* __restrict__ aout8, // [nwin*49,384] fp8
                                              int win_base) {
    __shared__ unsigned short Plds[4][64][72];
    __shared__ unsigned short Vlds[4][32][72];
    int tid = threadIdx.x;
    int w = tid >> 6, lane = tid & 63;
    int wg = blockIdx.x * 4 + w;
    int lw = wg / 12;                  // local window
    int h  = wg - lw * 12;             // head
    int g  = lane >> 4, c = lane & 15;
    const unsigned char* base = qkv8 + (long)lw * 49 * 1152;

    int wi = (win_base + lw) & 63;
    int mt = ((wi >> 3) == 7 ? 1 : 0) | ((wi & 7) == 7 ? 2 : 0);
    const float* tb = tbl + ((long)(mt * 12 + h) << 12);

    // ---- stage V (permuted rows) fp8->bf16 into LDS; zero-fill padding rows 49..63 ----
    #pragma unroll
    for (int it = 0; it < 4; ++it) {
        int t = it * 64 + lane;        // t < 256
        int j = t >> 2, o = t & 3;
        int pj = 4 * (j & 15) + (j >> 4);     // phys slot
        if (j < 49) {
            uint2 vv = *(const uint2*)(base + (long)j * 1152 + 768 + h * 32 + o * 8);
            Vlds[w][o * 8 + 0][pj] = f2bf(__builtin_amdgcn_cvt_f32_fp8(vv.x, 0));
            Vlds[w][o * 8 + 1][pj] = f2bf(__builtin_amdgcn_cvt_f32_fp8(vv.x, 1));
            Vlds[w][o * 8 + 2][pj] = f2bf(__builtin_amdgcn_cvt_f32_fp8(vv.x, 2));
            Vlds[w][o * 8 + 3][pj] = f2bf(__builtin_amdgcn_cvt_f32_fp8(vv.x, 3));
            Vlds[w][o * 8 + 4][pj] = f2bf(__builtin_amdgcn_cvt_f32_fp8(vv.y, 0));
            Vlds[w][o * 8 + 5][pj] = f2bf(__builtin_amdgcn_cvt_f32_fp8(vv.y, 1));
            Vlds[w][o * 8 + 6][pj] = f2bf(__builtin_amdgcn_cvt_f32_fp8(vv.y, 2));
            Vlds[w][o * 8 + 7][pj] = f2bf(__builtin_amdgcn_cvt_f32_fp8(vv.y, 3));
        } else {
            #pragma unroll
            for (int e = 0; e < 8; ++e) Vlds[w][o * 8 + e][pj] = 0;
        }
    }

    // ---- Q and K fp8 fragments straight from global (lane c: bytes 8g..8g+8 of row) ----
    long long qa8[4], kb8[4];
    #pragma unroll
    for (int m = 0; m < 4; ++m) {
        int qr = 16 * m + c; if (qr > 48) qr = 48;
        qa8[m] = *(const long long*)(base + (long)qr * 1152 + h * 32 + 8 * g);
    }
    #pragma unroll
    for (int n = 0; n < 4; ++n) {
        int jr = 16 * n + c; if (jr > 48) jr = 48;
        kb8[n] = *(const long long*)(base + (long)jr * 1152 + 384 + h * 32 + 8 * g);
    }

    // ---- S = Q.K^T : 16 fp8 MFMA, single k-step (K=hd=32) ----
    f32x4 s[4][4];
    #pragma unroll
    for (int m = 0; m < 4; ++m)
        #pragma unroll
        for (int n = 0; n < 4; ++n) {
            s[m][n] = (f32x4){0.f, 0.f, 0.f, 0.f};
            s[m][n] = __builtin_amdgcn_mfma_f32_16x16x32_fp8_fp8(qa8[m], kb8[n], s[m][n], 0, 0, 0);
        }

    // ---- scale + bias/mask table; softmax rows in C/D layout ----
    #pragma unroll
    for (int m = 0; m < 4; ++m)
        #pragma unroll
        for (int n = 0; n < 4; ++n) {
            #pragma unroll
            for (int ii = 0; ii < 4; ++ii) {
                int i = 16 * m + 4 * g + ii, j = 16 * n + c;
                s[m][n][ii] = s[m][n][ii] * 0.17677669529663687f + tb[i * 64 + j];
            }
        }
    float inv[4][4];
    #pragma unroll
    for (int m = 0; m < 4; ++m) {
        #pragma unroll
        for (int ii = 0; ii < 4; ++ii) {
            float mx = fmaxf(fmaxf(s[m][0][ii], s[m][1][ii]), fmaxf(s[m][2][ii], s[m][3][ii]));
            #pragma unroll
            for (int o = 1; o < 16; o <<= 1) mx = fmaxf(mx, __shfl_xor(mx, o));
            float sm = 0.f;
            #pragma unroll
            for (int n = 0; n < 4; ++n) {
                float p = __expf(s[m][n][ii] - mx);
                s[m][n][ii] = p; sm += p;
            }
            #pragma unroll
            for (int o = 1; o < 16; o <<= 1) sm += __shfl_xor(sm, o);
            inv[m][ii] = 1.f / sm;
        }
    }

    // ---- P -> LDS: packed b64 writes at permuted cols phys(16n+c)=4c+n ----
    #pragma unroll
    for (int m = 0; m < 4; ++m)
        #pragma unroll
        for (int ii = 0; ii < 4; ++ii) {
            int r = 16 * m + 4 * g + ii;
            u16x4 pk;
            #pragma unroll
            for (int n = 0; n < 4; ++n) pk[n] = f2bf(s[m][n][ii]);
            *(u16x4*)&Plds[w][r][4 * c] = pk;
        }

    __syncthreads();

    // ---- O = P.V : 2 bf16 k-steps over 64 phys slots ----
    f32x4 o2[4][2];
    #pragma unroll
    for (int m = 0; m < 4; ++m)
        #pragma unroll
        for (int n = 0; n < 2; ++n) o2[m][n] = (f32x4){0.f, 0.f, 0.f, 0.f};
    #pragma unroll
    for (int ks = 0; ks < 2; ++ks) {
        bf16x8 pa[4], vb[2];
        #pragma unroll
        for (int m = 0; m < 4; ++m)
            pa[m] = *(const bf16x8*)&Plds[w][c + 16 * m][32 * ks + 8 * g];
        #pragma unroll
        for (int n = 0; n < 2; ++n)
            vb[n] = *(const bf16x8*)&Vlds[w][c + 16 * n][32 * ks + 8 * g];
        #pragma unroll
        for (int m = 0; m < 4; ++m)
            #pragma unroll
            for (int n = 0; n < 2; ++n)
                o2[m][n] = __builtin_amdgcn_mfma_f32_16x16x32_bf16(pa[m], vb[n], o2[m][n], 0, 0, 0);
    }

    // ---- store O rows < 49 (fp8), scaled by 1/rowsum ----
    #pragma unroll
    for (int m = 0; m < 4; ++m)
        #pragma unroll
        for (int ii = 0; ii < 4; ++ii) {
            int i = 16 * m + 4 * g + ii;
            if (i < 49) {
                unsigned char* orow = aout8 + ((long)lw * 49 + i) * 384 + h * 32;
                #pragma unroll
                for (int n = 0; n < 2; ++n)
                    orow[c + 16 * n] = f2fp8(o2[m][n][ii] * inv[m][ii]);
            }
        }
}

// ---------------- fp8 MFMA GEMM: 256x128 tile, BK=128, 8 waves ----------------
// A[M,K] fp8 rm, Bt[N,K] fp8 rm. LDS 48 KB (2 blocks/CU). Swizzle: LDS chunk s of
// row r holds global chunk s^((r>>1)&3) (low-2-bit XOR; both sides). Read: chunk =
// (2kk+(g>>1))^((r>>1)&3), kk=0..3. Staging: 8 rows/issue (A:4, B:2 issues/wave),
// source chunk (lane&7)^((lane>>4)&3) invariant (row bases multiple of 8).
// EPI: 0 = bf16 out (proj), 1 = fp8 out + rcp-GELU (fc1), 2 = fp8 out (qkv),
//      3 = f32 out + res (fc2)
template<int EPI>
__global__ __launch_bounds__(512) void k_gemm8(
    const unsigned char* __restrict__ A,
    const unsigned char* __restrict__ Bt,
    const float* __restrict__ bias,
    unsigned short* outb16, unsigned char* outb8, float* outf, const float* res,
    int N, int K, int m_base)
{
    __shared__ unsigned char As[256][128];   // 32 KB
    __shared__ unsigned char Bs[128][128];   // 16 KB
    int nwg = gridDim.x * gridDim.y;
    int bid = blockIdx.y * gridDim.x + blockIdx.x;
    int qq = nwg >> 3, rr = nwg & 7;
    int xcd = bid & 7, idx = bid >> 3;
    int swz = (xcd < rr) ? (xcd * (qq + 1) + idx) : (rr * (qq + 1) + (xcd - rr) * qq + idx);
    int m0 = (swz / gridDim.x) << 8;
    int n0 = (swz % gridDim.x) << 7;

    int tid = threadIdx.x, wid = tid >> 6, lane = tid & 63;
    int wr = wid >> 1, wc = wid & 1;      // 4M x 2N waves, 64x64 out each
    f32x4 acc[4][4];
    #pragma unroll
    for (int i = 0; i < 4; ++i)
        #pragma unroll
        for (int j = 0; j < 4; ++j)
            acc[i][j] = (f32x4){0.f, 0.f, 0.f, 0.f};

    // staging: 8 rows per gload_lds issue (128 B/row, 8 lanes/row).
    int lrow = lane >> 3;                       // 0..7
    int lchk = (lane & 7) ^ ((lane >> 4) & 3);  // swizzled source chunk (invariant)
    const unsigned char* Ag = A  + (long)(m0 + wid * 32 + lrow) * K + lchk * 16;
    const unsigned char* Bg = Bt + (long)(n0 + wid * 16 + lrow) * K + lchk * 16;

    for (int k0 = 0; k0 < K; k0 += 128) {
        #pragma unroll
        for (int c = 0; c < 4; ++c)
            __builtin_amdgcn_global_load_lds(
                (const __attribute__((address_space(1))) void*)(Ag + k0 + (long)c * 8 * K),
                (__attribute__((address_space(3))) void*)(&As[wid * 32 + c * 8][0]), 16, 0, 0);
        #pragma unroll
        for (int c = 0; c < 2; ++c)
            __builtin_amdgcn_global_load_lds(
                (const __attribute__((address_space(1))) void*)(Bg + k0 + (long)c * 8 * K),
                (__attribute__((address_space(3))) void*)(&Bs[wid * 16 + c * 8][0]), 16, 0, 0);
        __syncthreads();
        #pragma unroll
        for (int kk = 0; kk < 4; ++kk) {
            long long af[4], bfr[4];
            int g = lane >> 4;
            #pragma unroll
            for (int mi = 0; mi < 4; ++mi) {
                int r = wr * 64 + mi * 16 + (lane & 15);
                int chunk = (2 * kk + (g >> 1)) ^ ((r >> 1) & 3);
                af[mi] = *reinterpret_cast<const long long*>(&As[r][chunk * 16 + (g & 1) * 8]);
            }
            #pragma unroll
            for (int ni = 0; ni < 4; ++ni) {
                int r = wc * 64 + ni * 16 + (lane & 15);
                int chunk = (2 * kk + (g >> 1)) ^ ((r >> 1) & 3);
                bfr[ni] = *reinterpret_cast<const long long*>(&Bs[r][chunk * 16 + (g & 1) * 8]);
            }
            #pragma unroll
            for (int mi = 0; mi < 4; ++mi)
                #pragma unroll
                for (int ni = 0; ni < 4; ++ni)
                    acc[mi][ni] = __builtin_amdgcn_mfma_f32_16x16x32_fp8_fp8(
                        af[mi], bfr[ni], acc[mi][ni], 0, 0, 0);
        }
        __syncthreads();
    }

    #pragma unroll
    for (int mi = 0; mi < 4; ++mi) {
        #pragma unroll
        for (int ni = 0; ni < 4; ++ni) {
            int col = n0 + wc * 64 + ni * 16 + (lane & 15);
            float bv = bias[col];
            #pragma unroll
            for (int i = 0; i < 4; ++i) {
                int row = m0 + wr * 64 + mi * 16 + (lane >> 4) * 4 + i;
                float v = acc[mi][ni][i] + bv;
                if constexpr (EPI == 0) {
                    outb16[(long)row * N + col] = f2bf(v);
                } else if constexpr (EPI == 1) {
                    // sigmoid-form GELU with HW rcp (no IEEE div)
                    float e = __expf(-(1.5957691f * v + 0.0713548f * v * v * v));
                    float gv = v * __builtin_amdgcn_rcpf(1.f + e);
                    outb8[(long)row * N + col] = f2fp8(gv);
                } else if constexpr (EPI == 2) {
                    outb8[(long)row * N + col] = f2fp8(v);
                } else {
                    long oidx = (long)(m_base + row) * 384 + col;
                    outf[oidx] = v + res[oidx];
                }
            }
        }
    }
}

extern "C" void kernel_launch(void* const* d_in, const int* in_sizes, int n_in,
                              void* d_out, int out_size, void* d_ws, size_t ws_size,
                              hipStream_t stream) {
    (void)in_sizes; (void)n_in; (void)out_size;
    const float* x     = (const float*)d_in[0];
    const float* n1g   = (const float*)d_in[1];
    const float* n1b   = (const float*)d_in[2];
    const float* qkvw  = (const float*)d_in[3];
    const float* qkvb  = (const float*)d_in[4];
    const float* rpb   = (const float*)d_in[5];
    const float* projw = (const float*)d_in[6];
    const float* projb = (const float*)d_in[7];
    const float* n2g   = (const float*)d_in[8];
    const float* n2b   = (const float*)d_in[9];
    const float* fc1w  = (const float*)d_in[10];
    const float* fc1b  = (const float*)d_in[11];
    const float* fc2w  = (const float*)d_in[12];
    const float* fc2b  = (const float*)d_in[13];
    float* out = (float*)d_out;

    const long Mtot = 200704;
    auto pad = [](size_t b) { return (b + 255) & ~(size_t)255; };
    size_t fixed = pad((size_t)1152 * 384) + pad((size_t)384 * 384)
                 + pad((size_t)1536 * 384) + pad((size_t)384 * 1536)
                 + pad((size_t)4 * 12 * 4096 * 4)
                 + pad((size_t)Mtot * 384)          // xw8 / h2 (fp8)
                 + pad((size_t)Mtot * 384 * 2);     // projout (bf16)
    int nc = 1;
    while (nc < 8) {
        size_t rows = Mtot / nc;
        if (fixed + pad(rows * 1536 * 2) + pad(rows * 384) <= ws_size) break;
        nc <<= 1;
    }
    long rows = Mtot / nc;            // rows per chunk, multiple of 256 and 49
    int  mb   = (int)(rows >> 8);     // 256-row tiles per chunk
    int  wpc  = (int)(rows / 49);     // windows per chunk (multiple of 64)

    char* ws = (char*)d_ws;
    size_t off = 0;
    auto alloc = [&](size_t bytes) { char* p = ws + off; off += (bytes + 255) & ~(size_t)255; return p; };
    unsigned char*  BtQ8 = (unsigned char*)alloc((size_t)1152 * 384);        // qkv weights fp8
    unsigned char*  BtP8 = (unsigned char*)alloc((size_t)384 * 384);         // proj weights fp8
    unsigned char*  Bt18 = (unsigned char*)alloc((size_t)1536 * 384);        // fc1 weights fp8
    unsigned char*  Bt28 = (unsigned char*)alloc((size_t)384 * 1536);        // fc2 weights fp8
    float*          tbl  = (float*)alloc((size_t)4 * 12 * 4096 * 4);
    unsigned char*  xw8  = (unsigned char*)alloc((size_t)Mtot * 384);        // fp8 xw; later fp8 h2
    unsigned short* pout = (unsigned short*)alloc((size_t)Mtot * 384 * 2);   // proj out (bf16, window order)
    unsigned char*  bufB8= (unsigned char*)alloc((size_t)rows * 1536 * 2);   // qkv fp8 (1152) / fc1 fp8 (1536)
    unsigned char*  attb8= (unsigned char*)alloc((size_t)rows * 384);        // attn-out fp8

    k_transpose8<<<dim3((1152 * 384 + 255) / 256), 256, 0, stream>>>(qkvw, BtQ8, 384, 1152);
    k_transpose8<<<dim3((384 * 384 + 255) / 256), 256, 0, stream>>>(projw, BtP8, 384, 384);
    k_transpose8<<<dim3((1536 * 384 + 255) / 256), 256, 0, stream>>>(fc1w, Bt18, 384, 1536);
    k_transpose8<<<dim3((384 * 1536 + 255) / 256), 256, 0, stream>>>(fc2w, Bt28, 1536, 384);
    k_btab<<<dim3(768), 256, 0, stream>>>(rpb, tbl);

    k_ln1<<<dim3(50176), 256, 0, stream>>>(x, n1g, n1b, xw8);

    // attention phase (all-fp8: qkv out fp8 -> fp8 QK^T attention -> fp8 attn-out)
    for (int c = 0; c < nc; ++c) {
        const unsigned char* Ax = xw8 + (size_t)c * rows * 384;
        k_gemm8<2><<<dim3(9, mb), 512, 0, stream>>>(Ax, BtQ8, qkvb, nullptr, bufB8, nullptr,
                                                    nullptr, 1152, 384, 0);
        k_attn<<<dim3(wpc * 3), 256, 0, stream>>>(bufB8, tbl, attb8, c * wpc);
        k_gemm8<0><<<dim3(3, mb), 512, 0, stream>>>(attb8, BtP8, projb,
                                                    pout + (size_t)c * rows * 384,
                                                    nullptr, nullptr, nullptr,
                                                    384, 384, 0);
    }

    // fused un-roll scatter + residual + LN2 (writes out f32 and h2 fp8 into xw buffer)
    k_scln<<<dim3(50176), 256, 0, stream>>>(pout, x, n2g, n2b, out, xw8);

    // MLP phase: fc1 fp8 GEMM (rcp-GELU, fp8 out); fc2 fp8 GEMM (+residual)
    for (int c = 0; c < nc; ++c) {
        const unsigned char* Ah = xw8 + (size_t)c * rows * 384;
        k_gemm8<1><<<dim3(12, mb), 512, 0, stream>>>(Ah, Bt18, fc1b, nullptr, bufB8, nullptr,
                                                     nullptr, 1536, 384, 0);
        k_gemm8<3><<<dim3(3, mb), 512, 0, stream>>>(bufB8, Bt28, fc2b, nullptr, nullptr, out,
                                                    out, 384, 1536, (int)(c * rows));
    }
}

// Round 21
// 1346.637 us; speedup vs baseline: 1.1016x; 1.1016x over previous
//
#include <hip/hip_runtime.h>

// Swin block (all-fp8 GEMMs + fp8 qkv edge): LN1(fp8) -> qkv fp8 GEMM(fp8 out)
//   -> MFMA attn (fp8 QK^T, bf16 PV, fp8 out) -> proj fp8 GEMM(bf16 out)
//   -> scatter+res+LN2(fp8 h2) -> fc1 fp8(+rcp-GELU, fp8 out) -> fc2 fp8(+residual)
// B=64, H=W=56, C=384, WS=7, SS=3, NH=12, hd=32, N=49, nW=64, B_=4096, M=200704
// R21: BK=128 retained, swizzle FIXED. R20's ^((r>>1)&3) only 4-way-spread a row
//      stride that is now a full 32-bank wrap (128 B) -> 4-way conflicts (8.67e7).
//      Correct: 3-bit XOR, LDS chunk p of row r holds global chunk p^(r&7)
//      (= the verified bf16 kernel's pattern at identical 128 B row stride, 0
//      conflicts). Store: lchk=(lane&7)^(lane>>3); read: chunk=(2kk+(g>>1))^(r&7)
//      -> 8 chunks x 2 lanes = 2-way (free, m136).

typedef __bf16 bf16x8 __attribute__((ext_vector_type(8)));
typedef float  f32x4  __attribute__((ext_vector_type(4)));
typedef unsigned short u16x4 __attribute__((ext_vector_type(4)));

__device__ __forceinline__ unsigned short f2bf(float f) {
    unsigned int u = __builtin_bit_cast(unsigned int, f);
    u += 0x7fffu + ((u >> 16) & 1u);   // RNE
    return (unsigned short)(u >> 16);
}
__device__ __forceinline__ float bf2f(unsigned short h) {
    return __builtin_bit_cast(float, (unsigned int)h << 16);
}
__device__ __forceinline__ unsigned char f2fp8(float f) {   // e4m3, RNE (HW)
    return (unsigned char)(__builtin_amdgcn_cvt_pk_fp8_f32(f, f, 0, false) & 0xff);
}

// ---------------- weight transpose + cast: W[K,N] f32 -> Bt[N,K] fp8 e4m3 ----------------
__global__ __launch_bounds__(256) void k_transpose8(const float* __restrict__ W,
                                                    unsigned char* __restrict__ Bt,
                                                    int K, int N) {
    int idx = blockIdx.x * 256 + threadIdx.x;
    if (idx >= N * K) return;
    int n = idx / K, k = idx - n * K;
    Bt[idx] = f2fp8(W[(long)k * N + n]);
}

// ---------------- bias+mask table: tbl[mt][h][i][j], 4*12*64*64 f32 ----------------
__global__ __launch_bounds__(256) void k_btab(const float* __restrict__ rpb,
                                              float* __restrict__ tbl) {
    int idx = blockIdx.x * 256 + threadIdx.x;
    if (idx >= 4 * 12 * 4096) return;
    int j = idx & 63, i = (idx >> 6) & 63;
    int slab = idx >> 12;            // mt*12 + h
    int h = slab % 12, mt = slab / 12;
    float v;
    if (j >= 49)      v = -30000.f;
    else if (i >= 49) v = 0.f;
    else {
        int ith = i / 7, itw = i - ith * 7;
        int jth = j / 7, jtw = j - jth * 7;
        v = rpb[((ith - jth + 6) * 13 + (itw - jtw + 6)) * 12 + h];
        bool m = ((mt & 1) && ((ith < 4) != (jth < 4))) ||
                 ((mt & 2) && ((itw < 4) != (jtw < 4)));
        if (m) v -= 100.f;
    }
    tbl[idx] = v;
}

// ---------------- LN1 + cyclic shift(-3,-3) + window partition -> fp8 ----------------
__global__ __launch_bounds__(256) void k_ln1(const float* __restrict__ x,
                                             const float* __restrict__ g,
                                             const float* __restrict__ bb,
                                             unsigned char* __restrict__ xw8) {
    int wid = threadIdx.x >> 6, lane = threadIdx.x & 63;
    int tok = blockIdx.x * 4 + wid;                 // < 200704
    int t  = tok % 49; int b_ = tok / 49;
    int wi = b_ & 63;  int b  = b_ >> 6;
    int th = t / 7, tw = t - th * 7;
    int hs = (wi >> 3) * 7 + th + 3; if (hs >= 56) hs -= 56;
    int vs = (wi & 7) * 7 + tw + 3;  if (vs >= 56) vs -= 56;
    const float2* row = (const float2*)(x + ((long)b * 3136 + hs * 56 + vs) * 384);
    float2 v[3]; float s = 0.f;
    #pragma unroll
    for (int i = 0; i < 3; ++i) { v[i] = row[lane + 64 * i]; s += v[i].x + v[i].y; }
    #pragma unroll
    for (int o = 32; o; o >>= 1) s += __shfl_xor(s, o);
    float mean = s * (1.f / 384.f);
    float q = 0.f;
    #pragma unroll
    for (int i = 0; i < 3; ++i) {
        float dx = v[i].x - mean, dy = v[i].y - mean; q += dx * dx + dy * dy;
    }
    #pragma unroll
    for (int o = 32; o; o >>= 1) q += __shfl_xor(q, o);
    float inv = rsqrtf(q * (1.f / 384.f) + 1e-5f);
    unsigned char* orow = xw8 + (long)tok * 384;
    #pragma unroll
    for (int i = 0; i < 3; ++i) {
        int c = i * 128 + lane * 2;
        unsigned short p = (unsigned short)f2fp8((v[i].x - mean) * inv * g[c] + bb[c])
                         | ((unsigned short)f2fp8((v[i].y - mean) * inv * g[c + 1] + bb[c + 1]) << 8);
        *(unsigned short*)(orow + c) = p;
    }
}

// ------- fused un-roll scatter + residual + LN2: out = x + gather(projout); h2 = LN2(out) fp8 -------
__global__ __launch_bounds__(256) void k_scln(const unsigned short* __restrict__ po,
                                              const float* __restrict__ x,
                                              const float* __restrict__ g,
                                              const float* __restrict__ bb,
                                              float* __restrict__ out,
                                              unsigned char* __restrict__ h2) {
    int wid = threadIdx.x >> 6, lane = threadIdx.x & 63;
    int tok = blockIdx.x * 4 + wid;                 // < 200704
    int b = tok / 3136, rem = tok - b * 3136;
    int hh = rem / 56, ww = rem - hh * 56;
    int u = (hh >= 3) ? hh - 3 : hh + 53;           // inverse roll(+3)
    int v = (ww >= 3) ? ww - 3 : ww + 53;
    int wr = u / 7, th = u - wr * 7;
    int wc = v / 7, tw = v - wc * 7;
    long src = ((long)((b << 6) + wr * 8 + wc) * 49 + th * 7 + tw) * 384;
    const unsigned int* prow = (const unsigned int*)(po + src);    // 2 bf16 / uint
    const float2* xrow = (const float2*)(x + (long)tok * 384);
    float2 o[3]; float s = 0.f;
    #pragma unroll
    for (int i = 0; i < 3; ++i) {
        unsigned int pb = prow[lane + 64 * i];
        float2 xv = xrow[lane + 64 * i];
        o[i].x = xv.x + bf2f((unsigned short)(pb & 0xffffu));
        o[i].y = xv.y + bf2f((unsigned short)(pb >> 16));
        s += o[i].x + o[i].y;
    }
    float2* orow = (float2*)(out + (long)tok * 384);
    #pragma unroll
    for (int i = 0; i < 3; ++i) orow[lane + 64 * i] = o[i];
    #pragma unroll
    for (int of = 32; of; of >>= 1) s += __shfl_xor(s, of);
    float mean = s * (1.f / 384.f);
    float q = 0.f;
    #pragma unroll
    for (int i = 0; i < 3; ++i) {
        float dx = o[i].x - mean, dy = o[i].y - mean; q += dx * dx + dy * dy;
    }
    #pragma unroll
    for (int of = 32; of; of >>= 1) q += __shfl_xor(q, of);
    float inv = rsqrtf(q * (1.f / 384.f) + 1e-5f);
    unsigned char* hrow = h2 + (long)tok * 384;
    #pragma unroll
    for (int i = 0; i < 3; ++i) {
        int c = i * 128 + lane * 2;
        unsigned short p = (unsigned short)f2fp8((o[i].x - mean) * inv * g[c] + bb[c])
                         | ((unsigned short)f2fp8((o[i].y - mean) * inv * g[c + 1] + bb[c + 1]) << 8);
        *(unsigned short*)(hrow + c) = p;
    }
}

// ---------------- MFMA windowed attention: 1 wave = 1 (window, head), 4 waves/block ----------------
// reads fp8 qkv; QK^T via fp8 MFMA; V converted fp8->bf16 at staging (PV bf16 MFMA);
// writes fp8 attn-out (proj GEMM input).
__global__ __launch_bounds__(256) void k_attn(const unsigned char* __restrict__ qkv8,
                                              const float* __restrict__ tbl,     // [4][12][64][64]
                                              unsigned char* __restrict__ aout8, // [nwin*49,384] fp8
                                              int win_base) {
    __shared__ unsigned short Plds[4][64][72];
    __shared__ unsigned short Vlds[4][32][72];
    int tid = threadIdx.x;
    int w = tid >> 6, lane = tid & 63;
    int wg = blockIdx.x * 4 + w;
    int lw = wg / 12;                  // local window
    int h  = wg - lw * 12;             // head
    int g  = lane >> 4, c = lane & 15;
    const unsigned char* base = qkv8 + (long)lw * 49 * 1152;

    int wi = (win_base + lw) & 63;
    int mt = ((wi >> 3) == 7 ? 1 : 0) | ((wi & 7) == 7 ? 2 : 0);
    const float* tb = tbl + ((long)(mt * 12 + h) << 12);

    // ---- stage V (permuted rows) fp8->bf16 into LDS; zero-fill padding rows 49..63 ----
    #pragma unroll
    for (int it = 0; it < 4; ++it) {
        int t = it * 64 + lane;        // t < 256
        int j = t >> 2, o = t & 3;
        int pj = 4 * (j & 15) + (j >> 4);     // phys slot
        if (j < 49) {
            uint2 vv = *(const uint2*)(base + (long)j * 1152 + 768 + h * 32 + o * 8);
            Vlds[w][o * 8 + 0][pj] = f2bf(__builtin_amdgcn_cvt_f32_fp8(vv.x, 0));
            Vlds[w][o * 8 + 1][pj] = f2bf(__builtin_amdgcn_cvt_f32_fp8(vv.x, 1));
            Vlds[w][o * 8 + 2][pj] = f2bf(__builtin_amdgcn_cvt_f32_fp8(vv.x, 2));
            Vlds[w][o * 8 + 3][pj] = f2bf(__builtin_amdgcn_cvt_f32_fp8(vv.x, 3));
            Vlds[w][o * 8 + 4][pj] = f2bf(__builtin_amdgcn_cvt_f32_fp8(vv.y, 0));
            Vlds[w][o * 8 + 5][pj] = f2bf(__builtin_amdgcn_cvt_f32_fp8(vv.y, 1));
            Vlds[w][o * 8 + 6][pj] = f2bf(__builtin_amdgcn_cvt_f32_fp8(vv.y, 2));
            Vlds[w][o * 8 + 7][pj] = f2bf(__builtin_amdgcn_cvt_f32_fp8(vv.y, 3));
        } else {
            #pragma unroll
            for (int e = 0; e < 8; ++e) Vlds[w][o * 8 + e][pj] = 0;
        }
    }

    // ---- Q and K fp8 fragments straight from global (lane c: bytes 8g..8g+8 of row) ----
    long long qa8[4], kb8[4];
    #pragma unroll
    for (int m = 0; m < 4; ++m) {
        int qr = 16 * m + c; if (qr > 48) qr = 48;
        qa8[m] = *(const long long*)(base + (long)qr * 1152 + h * 32 + 8 * g);
    }
    #pragma unroll
    for (int n = 0; n < 4; ++n) {
        int jr = 16 * n + c; if (jr > 48) jr = 48;
        kb8[n] = *(const long long*)(base + (long)jr * 1152 + 384 + h * 32 + 8 * g);
    }

    // ---- S = Q.K^T : 16 fp8 MFMA, single k-step (K=hd=32) ----
    f32x4 s[4][4];
    #pragma unroll
    for (int m = 0; m < 4; ++m)
        #pragma unroll
        for (int n = 0; n < 4; ++n) {
            s[m][n] = (f32x4){0.f, 0.f, 0.f, 0.f};
            s[m][n] = __builtin_amdgcn_mfma_f32_16x16x32_fp8_fp8(qa8[m], kb8[n], s[m][n], 0, 0, 0);
        }

    // ---- scale + bias/mask table; softmax rows in C/D layout ----
    #pragma unroll
    for (int m = 0; m < 4; ++m)
        #pragma unroll
        for (int n = 0; n < 4; ++n) {
            #pragma unroll
            for (int ii = 0; ii < 4; ++ii) {
                int i = 16 * m + 4 * g + ii, j = 16 * n + c;
                s[m][n][ii] = s[m][n][ii] * 0.17677669529663687f + tb[i * 64 + j];
            }
        }
    float inv[4][4];
    #pragma unroll
    for (int m = 0; m < 4; ++m) {
        #pragma unroll
        for (int ii = 0; ii < 4; ++ii) {
            float mx = fmaxf(fmaxf(s[m][0][ii], s[m][1][ii]), fmaxf(s[m][2][ii], s[m][3][ii]));
            #pragma unroll
            for (int o = 1; o < 16; o <<= 1) mx = fmaxf(mx, __shfl_xor(mx, o));
            float sm = 0.f;
            #pragma unroll
            for (int n = 0; n < 4; ++n) {
                float p = __expf(s[m][n][ii] - mx);
                s[m][n][ii] = p; sm += p;
            }
            #pragma unroll
            for (int o = 1; o < 16; o <<= 1) sm += __shfl_xor(sm, o);
            inv[m][ii] = 1.f / sm;
        }
    }

    // ---- P -> LDS: packed b64 writes at permuted cols phys(16n+c)=4c+n ----
    #pragma unroll
    for (int m = 0; m < 4; ++m)
        #pragma unroll
        for (int ii = 0; ii < 4; ++ii) {
            int r = 16 * m + 4 * g + ii;
            u16x4 pk;
            #pragma unroll
            for (int n = 0; n < 4; ++n) pk[n] = f2bf(s[m][n][ii]);
            *(u16x4*)&Plds[w][r][4 * c] = pk;
        }

    __syncthreads();

    // ---- O = P.V : 2 bf16 k-steps over 64 phys slots ----
    f32x4 o2[4][2];
    #pragma unroll
    for (int m = 0; m < 4; ++m)
        #pragma unroll
        for (int n = 0; n < 2; ++n) o2[m][n] = (f32x4){0.f, 0.f, 0.f, 0.f};
    #pragma unroll
    for (int ks = 0; ks < 2; ++ks) {
        bf16x8 pa[4], vb[2];
        #pragma unroll
        for (int m = 0; m < 4; ++m)
            pa[m] = *(const bf16x8*)&Plds[w][c + 16 * m][32 * ks + 8 * g];
        #pragma unroll
        for (int n = 0; n < 2; ++n)
            vb[n] = *(const bf16x8*)&Vlds[w][c + 16 * n][32 * ks + 8 * g];
        #pragma unroll
        for (int m = 0; m < 4; ++m)
            #pragma unroll
            for (int n = 0; n < 2; ++n)
                o2[m][n] = __builtin_amdgcn_mfma_f32_16x16x32_bf16(pa[m], vb[n], o2[m][n], 0, 0, 0);
    }

    // ---- store O rows < 49 (fp8), scaled by 1/rowsum ----
    #pragma unroll
    for (int m = 0; m < 4; ++m)
        #pragma unroll
        for (int ii = 0; ii < 4; ++ii) {
            int i = 16 * m + 4 * g + ii;
            if (i < 49) {
                unsigned char* orow = aout8 + ((long)lw * 49 + i) * 384 + h * 32;
                #pragma unroll
                for (int n = 0; n < 2; ++n)
                    orow[c + 16 * n] = f2fp8(o2[m][n][ii] * inv[m][ii]);
            }
        }
}

// ---------------- fp8 MFMA GEMM: 256x128 tile, BK=128, 8 waves ----------------
// A[M,K] fp8 rm, Bt[N,K] fp8 rm. LDS 48 KB (2 blocks/CU). Row stride 128 B = full
// 32-bank wrap -> 3-bit swizzle: LDS chunk p of row r holds global chunk p^(r&7)
// (= verified bf16 pattern at the same stride). Store: lchk=(lane&7)^(lane>>3)
// (row bases multiple of 8 -> r&7 = lane>>3). Read: chunk=(2kk+(g>>1))^(r&7),
// kk=0..3 -> 8 chunks x 2 lanes/bank = 2-way (free, m136).
// EPI: 0 = bf16 out (proj), 1 = fp8 out + rcp-GELU (fc1), 2 = fp8 out (qkv),
//      3 = f32 out + res (fc2)
template<int EPI>
__global__ __launch_bounds__(512) void k_gemm8(
    const unsigned char* __restrict__ A,
    const unsigned char* __restrict__ Bt,
    const float* __restrict__ bias,
    unsigned short* outb16, unsigned char* outb8, float* outf, const float* res,
    int N, int K, int m_base)
{
    __shared__ unsigned char As[256][128];   // 32 KB
    __shared__ unsigned char Bs[128][128];   // 16 KB
    int nwg = gridDim.x * gridDim.y;
    int bid = blockIdx.y * gridDim.x + blockIdx.x;
    int qq = nwg >> 3, rr = nwg & 7;
    int xcd = bid & 7, idx = bid >> 3;
    int swz = (xcd < rr) ? (xcd * (qq + 1) + idx) : (rr * (qq + 1) + (xcd - rr) * qq + idx);
    int m0 = (swz / gridDim.x) << 8;
    int n0 = (swz % gridDim.x) << 7;

    int tid = threadIdx.x, wid = tid >> 6, lane = tid & 63;
    int wr = wid >> 1, wc = wid & 1;      // 4M x 2N waves, 64x64 out each
    f32x4 acc[4][4];
    #pragma unroll
    for (int i = 0; i < 4; ++i)
        #pragma unroll
        for (int j = 0; j < 4; ++j)
            acc[i][j] = (f32x4){0.f, 0.f, 0.f, 0.f};

    // staging: 8 rows per gload_lds issue (128 B/row, 8 lanes/row).
    int lrow = lane >> 3;                  // 0..7
    int lchk = (lane & 7) ^ lrow;          // swizzled source chunk (3-bit, invariant)
    const unsigned char* Ag = A  + (long)(m0 + wid * 32 + lrow) * K + lchk * 16;
    const unsigned char* Bg = Bt + (long)(n0 + wid * 16 + lrow) * K + lchk * 16;

    for (int k0 = 0; k0 < K; k0 += 128) {
        #pragma unroll
        for (int c = 0; c < 4; ++c)
            __builtin_amdgcn_global_load_lds(
                (const __attribute__((address_space(1))) void*)(Ag + k0 + (long)c * 8 * K),
                (__attribute__((address_space(3))) void*)(&As[wid * 32 + c * 8][0]), 16, 0, 0);
        #pragma unroll
        for (int c = 0; c < 2; ++c)
            __builtin_amdgcn_global_load_lds(
                (const __attribute__((address_space(1))) void*)(Bg + k0 + (long)c * 8 * K),
                (__attribute__((address_space(3))) void*)(&Bs[wid * 16 + c * 8][0]), 16, 0, 0);
        __syncthreads();
        #pragma unroll
        for (int kk = 0; kk < 4; ++kk) {
            long long af[4], bfr[4];
            int g = lane >> 4;
            #pragma unroll
            for (int mi = 0; mi < 4; ++mi) {
                int r = wr * 64 + mi * 16 + (lane & 15);
                int chunk = (2 * kk + (g >> 1)) ^ (r & 7);
                af[mi] = *reinterpret_cast<const long long*>(&As[r][chunk * 16 + (g & 1) * 8]);
            }
            #pragma unroll
            for (int ni = 0; ni < 4; ++ni) {
                int r = wc * 64 + ni * 16 + (lane & 15);
                int chunk = (2 * kk + (g >> 1)) ^ (r & 7);
                bfr[ni] = *reinterpret_cast<const long long*>(&Bs[r][chunk * 16 + (g & 1) * 8]);
            }
            #pragma unroll
            for (int mi = 0; mi < 4; ++mi)
                #pragma unroll
                for (int ni = 0; ni < 4; ++ni)
                    acc[mi][ni] = __builtin_amdgcn_mfma_f32_16x16x32_fp8_fp8(
                        af[mi], bfr[ni], acc[mi][ni], 0, 0, 0);
        }
        __syncthreads();
    }

    #pragma unroll
    for (int mi = 0; mi < 4; ++mi) {
        #pragma unroll
        for (int ni = 0; ni < 4; ++ni) {
            int col = n0 + wc * 64 + ni * 16 + (lane & 15);
            float bv = bias[col];
            #pragma unroll
            for (int i = 0; i < 4; ++i) {
                int row = m0 + wr * 64 + mi * 16 + (lane >> 4) * 4 + i;
                float v = acc[mi][ni][i] + bv;
                if constexpr (EPI == 0) {
                    outb16[(long)row * N + col] = f2bf(v);
                } else if constexpr (EPI == 1) {
                    // sigmoid-form GELU with HW rcp (no IEEE div)
                    float e = __expf(-(1.5957691f * v + 0.0713548f * v * v * v));
                    float gv = v * __builtin_amdgcn_rcpf(1.f + e);
                    outb8[(long)row * N + col] = f2fp8(gv);
                } else if constexpr (EPI == 2) {
                    outb8[(long)row * N + col] = f2fp8(v);
                } else {
                    long oidx = (long)(m_base + row) * 384 + col;
                    outf[oidx] = v + res[oidx];
                }
            }
        }
    }
}

extern "C" void kernel_launch(void* const* d_in, const int* in_sizes, int n_in,
                              void* d_out, int out_size, void* d_ws, size_t ws_size,
                              hipStream_t stream) {
    (void)in_sizes; (void)n_in; (void)out_size;
    const float* x     = (const float*)d_in[0];
    const float* n1g   = (const float*)d_in[1];
    const float* n1b   = (const float*)d_in[2];
    const float* qkvw  = (const float*)d_in[3];
    const float* qkvb  = (const float*)d_in[4];
    const float* rpb   = (const float*)d_in[5];
    const float* projw = (const float*)d_in[6];
    const float* projb = (const float*)d_in[7];
    const float* n2g   = (const float*)d_in[8];
    const float* n2b   = (const float*)d_in[9];
    const float* fc1w  = (const float*)d_in[10];
    const float* fc1b  = (const float*)d_in[11];
    const float* fc2w  = (const float*)d_in[12];
    const float* fc2b  = (const float*)d_in[13];
    float* out = (float*)d_out;

    const long Mtot = 200704;
    auto pad = [](size_t b) { return (b + 255) & ~(size_t)255; };
    size_t fixed = pad((size_t)1152 * 384) + pad((size_t)384 * 384)
                 + pad((size_t)1536 * 384) + pad((size_t)384 * 1536)
                 + pad((size_t)4 * 12 * 4096 * 4)
                 + pad((size_t)Mtot * 384)          // xw8 / h2 (fp8)
                 + pad((size_t)Mtot * 384 * 2);     // projout (bf16)
    int nc = 1;
    while (nc < 8) {
        size_t rows = Mtot / nc;
        if (fixed + pad(rows * 1536 * 2) + pad(rows * 384) <= ws_size) break;
        nc <<= 1;
    }
    long rows = Mtot / nc;            // rows per chunk, multiple of 256 and 49
    int  mb   = (int)(rows >> 8);     // 256-row tiles per chunk
    int  wpc  = (int)(rows / 49);     // windows per chunk (multiple of 64)

    char* ws = (char*)d_ws;
    size_t off = 0;
    auto alloc = [&](size_t bytes) { char* p = ws + off; off += (bytes + 255) & ~(size_t)255; return p; };
    unsigned char*  BtQ8 = (unsigned char*)alloc((size_t)1152 * 384);        // qkv weights fp8
    unsigned char*  BtP8 = (unsigned char*)alloc((size_t)384 * 384);         // proj weights fp8
    unsigned char*  Bt18 = (unsigned char*)alloc((size_t)1536 * 384);        // fc1 weights fp8
    unsigned char*  Bt28 = (unsigned char*)alloc((size_t)384 * 1536);        // fc2 weights fp8
    float*          tbl  = (float*)alloc((size_t)4 * 12 * 4096 * 4);
    unsigned char*  xw8  = (unsigned char*)alloc((size_t)Mtot * 384);        // fp8 xw; later fp8 h2
    unsigned short* pout = (unsigned short*)alloc((size_t)Mtot * 384 * 2);   // proj out (bf16, window order)
    unsigned char*  bufB8= (unsigned char*)alloc((size_t)rows * 1536 * 2);   // qkv fp8 (1152) / fc1 fp8 (1536)
    unsigned char*  attb8= (unsigned char*)alloc((size_t)rows * 384);        // attn-out fp8

    k_transpose8<<<dim3((1152 * 384 + 255) / 256), 256, 0, stream>>>(qkvw, BtQ8, 384, 1152);
    k_transpose8<<<dim3((384 * 384 + 255) / 256), 256, 0, stream>>>(projw, BtP8, 384, 384);
    k_transpose8<<<dim3((1536 * 384 + 255) / 256), 256, 0, stream>>>(fc1w, Bt18, 384, 1536);
    k_transpose8<<<dim3((384 * 1536 + 255) / 256), 256, 0, stream>>>(fc2w, Bt28, 1536, 384);
    k_btab<<<dim3(768), 256, 0, stream>>>(rpb, tbl);

    k_ln1<<<dim3(50176), 256, 0, stream>>>(x, n1g, n1b, xw8);

    // attention phase (all-fp8: qkv out fp8 -> fp8 QK^T attention -> fp8 attn-out)
    for (int c = 0; c < nc; ++c) {
        const unsigned char* Ax = xw8 + (size_t)c * rows * 384;
        k_gemm8<2><<<dim3(9, mb), 512, 0, stream>>>(Ax, BtQ8, qkvb, nullptr, bufB8, nullptr,
                                                    nullptr, 1152, 384, 0);
        k_attn<<<dim3(wpc * 3), 256, 0, stream>>>(bufB8, tbl, attb8, c * wpc);
        k_gemm8<0><<<dim3(3, mb), 512, 0, stream>>>(attb8, BtP8, projb,
                                                    pout + (size_t)c * rows * 384,
                                                    nullptr, nullptr, nullptr,
                                                    384, 384, 0);
    }

    // fused un-roll scatter + residual + LN2 (writes out f32 and h2 fp8 into xw buffer)
    k_scln<<<dim3(50176), 256, 0, stream>>>(pout, x, n2g, n2b, out, xw8);

    // MLP phase: fc1 fp8 GEMM (rcp-GELU, fp8 out); fc2 fp8 GEMM (+residual)
    for (int c = 0; c < nc; ++c) {
        const unsigned char* Ah = xw8 + (size_t)c * rows * 384;
        k_gemm8<1><<<dim3(12, mb), 512, 0, stream>>>(Ah, Bt18, fc1b, nullptr, bufB8, nullptr,
                                                     nullptr, 1536, 384, 0);
        k_gemm8<3><<<dim3(3, mb), 512, 0, stream>>>(bufB8, Bt28, fc2b, nullptr, nullptr, out,
                                                    out, 384, 1536, (int)(c * rows));
    }
}

// Round 22
// 1230.117 us; speedup vs baseline: 1.2059x; 1.0947x over previous
//
#include <hip/hip_runtime.h>

// Swin block (all-fp8 GEMMs, bf16 residual edge): LN1(fp8) -> qkv fp8(fp8 out)
//   -> MFMA attn (fp8 QK^T, bf16 PV, fp8 out) -> proj fp8(bf16 out)
//   -> scatter+res+LN2(bf16 out1, fp8 h2) -> fc1 fp8(+rcp-GELU, fp8 out)
//   -> fc2 fp8(+bf16 residual -> f32 d_out)
// B=64, H=W=56, C=384, WS=7, SS=3, NH=12, hd=32, N=49, nW=64, B_=4096, M=200704
// R22: residual edge to bf16 (last f32 bulk traffic): scln writes out1 = x+proj as
//      bf16 into o1b (154 vs 305 MB); fc2 reads o1b and writes final f32 d_out (only
//      writer, full coverage). Saves ~300 MB of f32 traffic on the scln+fc2 path.
//      bufB8 right-sized to fp8 (rows x 1536 B). R21's BK=128 + 3-bit swizzle kept.

typedef __bf16 bf16x8 __attribute__((ext_vector_type(8)));
typedef float  f32x4  __attribute__((ext_vector_type(4)));
typedef unsigned short u16x4 __attribute__((ext_vector_type(4)));

__device__ __forceinline__ unsigned short f2bf(float f) {
    unsigned int u = __builtin_bit_cast(unsigned int, f);
    u += 0x7fffu + ((u >> 16) & 1u);   // RNE
    return (unsigned short)(u >> 16);
}
__device__ __forceinline__ float bf2f(unsigned short h) {
    return __builtin_bit_cast(float, (unsigned int)h << 16);
}
__device__ __forceinline__ unsigned char f2fp8(float f) {   // e4m3, RNE (HW)
    return (unsigned char)(__builtin_amdgcn_cvt_pk_fp8_f32(f, f, 0, false) & 0xff);
}

// ---------------- weight transpose + cast: W[K,N] f32 -> Bt[N,K] fp8 e4m3 ----------------
__global__ __launch_bounds__(256) void k_transpose8(const float* __restrict__ W,
                                                    unsigned char* __restrict__ Bt,
                                                    int K, int N) {
    int idx = blockIdx.x * 256 + threadIdx.x;
    if (idx >= N * K) return;
    int n = idx / K, k = idx - n * K;
    Bt[idx] = f2fp8(W[(long)k * N + n]);
}

// ---------------- bias+mask table: tbl[mt][h][i][j], 4*12*64*64 f32 ----------------
__global__ __launch_bounds__(256) void k_btab(const float* __restrict__ rpb,
                                              float* __restrict__ tbl) {
    int idx = blockIdx.x * 256 + threadIdx.x;
    if (idx >= 4 * 12 * 4096) return;
    int j = idx & 63, i = (idx >> 6) & 63;
    int slab = idx >> 12;            // mt*12 + h
    int h = slab % 12, mt = slab / 12;
    float v;
    if (j >= 49)      v = -30000.f;
    else if (i >= 49) v = 0.f;
    else {
        int ith = i / 7, itw = i - ith * 7;
        int jth = j / 7, jtw = j - jth * 7;
        v = rpb[((ith - jth + 6) * 13 + (itw - jtw + 6)) * 12 + h];
        bool m = ((mt & 1) && ((ith < 4) != (jth < 4))) ||
                 ((mt & 2) && ((itw < 4) != (jtw < 4)));
        if (m) v -= 100.f;
    }
    tbl[idx] = v;
}

// ---------------- LN1 + cyclic shift(-3,-3) + window partition -> fp8 ----------------
__global__ __launch_bounds__(256) void k_ln1(const float* __restrict__ x,
                                             const float* __restrict__ g,
                                             const float* __restrict__ bb,
                                             unsigned char* __restrict__ xw8) {
    int wid = threadIdx.x >> 6, lane = threadIdx.x & 63;
    int tok = blockIdx.x * 4 + wid;                 // < 200704
    int t  = tok % 49; int b_ = tok / 49;
    int wi = b_ & 63;  int b  = b_ >> 6;
    int th = t / 7, tw = t - th * 7;
    int hs = (wi >> 3) * 7 + th + 3; if (hs >= 56) hs -= 56;
    int vs = (wi & 7) * 7 + tw + 3;  if (vs >= 56) vs -= 56;
    const float2* row = (const float2*)(x + ((long)b * 3136 + hs * 56 + vs) * 384);
    float2 v[3]; float s = 0.f;
    #pragma unroll
    for (int i = 0; i < 3; ++i) { v[i] = row[lane + 64 * i]; s += v[i].x + v[i].y; }
    #pragma unroll
    for (int o = 32; o; o >>= 1) s += __shfl_xor(s, o);
    float mean = s * (1.f / 384.f);
    float q = 0.f;
    #pragma unroll
    for (int i = 0; i < 3; ++i) {
        float dx = v[i].x - mean, dy = v[i].y - mean; q += dx * dx + dy * dy;
    }
    #pragma unroll
    for (int o = 32; o; o >>= 1) q += __shfl_xor(q, o);
    float inv = rsqrtf(q * (1.f / 384.f) + 1e-5f);
    unsigned char* orow = xw8 + (long)tok * 384;
    #pragma unroll
    for (int i = 0; i < 3; ++i) {
        int c = i * 128 + lane * 2;
        unsigned short p = (unsigned short)f2fp8((v[i].x - mean) * inv * g[c] + bb[c])
                         | ((unsigned short)f2fp8((v[i].y - mean) * inv * g[c + 1] + bb[c + 1]) << 8);
        *(unsigned short*)(orow + c) = p;
    }
}

// ------- fused un-roll scatter + residual + LN2: o1b = bf16(x + gather(projout)); h2 = LN2 fp8 -------
__global__ __launch_bounds__(256) void k_scln(const unsigned short* __restrict__ po,
                                              const float* __restrict__ x,
                                              const float* __restrict__ g,
                                              const float* __restrict__ bb,
                                              unsigned short* __restrict__ o1b,
                                              unsigned char* __restrict__ h2) {
    int wid = threadIdx.x >> 6, lane = threadIdx.x & 63;
    int tok = blockIdx.x * 4 + wid;                 // < 200704
    int b = tok / 3136, rem = tok - b * 3136;
    int hh = rem / 56, ww = rem - hh * 56;
    int u = (hh >= 3) ? hh - 3 : hh + 53;           // inverse roll(+3)
    int v = (ww >= 3) ? ww - 3 : ww + 53;
    int wr = u / 7, th = u - wr * 7;
    int wc = v / 7, tw = v - wc * 7;
    long src = ((long)((b << 6) + wr * 8 + wc) * 49 + th * 7 + tw) * 384;
    const unsigned int* prow = (const unsigned int*)(po + src);    // 2 bf16 / uint
    const float2* xrow = (const float2*)(x + (long)tok * 384);
    float2 o[3]; float s = 0.f;
    #pragma unroll
    for (int i = 0; i < 3; ++i) {
        unsigned int pb = prow[lane + 64 * i];
        float2 xv = xrow[lane + 64 * i];
        o[i].x = xv.x + bf2f((unsigned short)(pb & 0xffffu));
        o[i].y = xv.y + bf2f((unsigned short)(pb >> 16));
        s += o[i].x + o[i].y;
    }
    unsigned short* orow = o1b + (long)tok * 384;
    #pragma unroll
    for (int i = 0; i < 3; ++i) {
        int c = i * 128 + lane * 2;
        unsigned int p = (unsigned int)f2bf(o[i].x) | ((unsigned int)f2bf(o[i].y) << 16);
        *(unsigned int*)(orow + c) = p;
    }
    #pragma unroll
    for (int of = 32; of; of >>= 1) s += __shfl_xor(s, of);
    float mean = s * (1.f / 384.f);
    float q = 0.f;
    #pragma unroll
    for (int i = 0; i < 3; ++i) {
        float dx = o[i].x - mean, dy = o[i].y - mean; q += dx * dx + dy * dy;
    }
    #pragma unroll
    for (int of = 32; of; of >>= 1) q += __shfl_xor(q, of);
    float inv = rsqrtf(q * (1.f / 384.f) + 1e-5f);
    unsigned char* hrow = h2 + (long)tok * 384;
    #pragma unroll
    for (int i = 0; i < 3; ++i) {
        int c = i * 128 + lane * 2;
        unsigned short p = (unsigned short)f2fp8((o[i].x - mean) * inv * g[c] + bb[c])
                         | ((unsigned short)f2fp8((o[i].y - mean) * inv * g[c + 1] + bb[c + 1]) << 8);
        *(unsigned short*)(hrow + c) = p;
    }
}

// ---------------- MFMA windowed attention: 1 wave = 1 (window, head), 4 waves/block ----------------
__global__ __launch_bounds__(256) void k_attn(const unsigned char* __restrict__ qkv8,
                                              const float* __restrict__ tbl,     // [4][12][64][64]
                                              unsigned char* __restrict__ aout8, // [nwin*49,384] fp8
                                              int win_base) {
    __shared__ unsigned short Plds[4][64][72];
    __shared__ unsigned short Vlds[4][32][72];
    int tid = threadIdx.x;
    int w = tid >> 6, lane = tid & 63;
    int wg = blockIdx.x * 4 + w;
    int lw = wg / 12;                  // local window
    int h  = wg - lw * 12;             // head
    int g  = lane >> 4, c = lane & 15;
    const unsigned char* base = qkv8 + (long)lw * 49 * 1152;

    int wi = (win_base + lw) & 63;
    int mt = ((wi >> 3) == 7 ? 1 : 0) | ((wi & 7) == 7 ? 2 : 0);
    const float* tb = tbl + ((long)(mt * 12 + h) << 12);

    // ---- stage V (permuted rows) fp8->bf16 into LDS; zero-fill padding rows 49..63 ----
    #pragma unroll
    for (int it = 0; it < 4; ++it) {
        int t = it * 64 + lane;        // t < 256
        int j = t >> 2, o = t & 3;
        int pj = 4 * (j & 15) + (j >> 4);     // phys slot
        if (j < 49) {
            uint2 vv = *(const uint2*)(base + (long)j * 1152 + 768 + h * 32 + o * 8);
            Vlds[w][o * 8 + 0][pj] = f2bf(__builtin_amdgcn_cvt_f32_fp8(vv.x, 0));
            Vlds[w][o * 8 + 1][pj] = f2bf(__builtin_amdgcn_cvt_f32_fp8(vv.x, 1));
            Vlds[w][o * 8 + 2][pj] = f2bf(__builtin_amdgcn_cvt_f32_fp8(vv.x, 2));
            Vlds[w][o * 8 + 3][pj] = f2bf(__builtin_amdgcn_cvt_f32_fp8(vv.x, 3));
            Vlds[w][o * 8 + 4][pj] = f2bf(__builtin_amdgcn_cvt_f32_fp8(vv.y, 0));
            Vlds[w][o * 8 + 5][pj] = f2bf(__builtin_amdgcn_cvt_f32_fp8(vv.y, 1));
            Vlds[w][o * 8 + 6][pj] = f2bf(__builtin_amdgcn_cvt_f32_fp8(vv.y, 2));
            Vlds[w][o * 8 + 7][pj] = f2bf(__builtin_amdgcn_cvt_f32_fp8(vv.y, 3));
        } else {
            #pragma unroll
            for (int e = 0; e < 8; ++e) Vlds[w][o * 8 + e][pj] = 0;
        }
    }

    // ---- Q and K fp8 fragments straight from global (lane c: bytes 8g..8g+8 of row) ----
    long long qa8[4], kb8[4];
    #pragma unroll
    for (int m = 0; m < 4; ++m) {
        int qr = 16 * m + c; if (qr > 48) qr = 48;
        qa8[m] = *(const long long*)(base + (long)qr * 1152 + h * 32 + 8 * g);
    }
    #pragma unroll
    for (int n = 0; n < 4; ++n) {
        int jr = 16 * n + c; if (jr > 48) jr = 48;
        kb8[n] = *(const long long*)(base + (long)jr * 1152 + 384 + h * 32 + 8 * g);
    }

    // ---- S = Q.K^T : 16 fp8 MFMA, single k-step (K=hd=32) ----
    f32x4 s[4][4];
    #pragma unroll
    for (int m = 0; m < 4; ++m)
        #pragma unroll
        for (int n = 0; n < 4; ++n) {
            s[m][n] = (f32x4){0.f, 0.f, 0.f, 0.f};
            s[m][n] = __builtin_amdgcn_mfma_f32_16x16x32_fp8_fp8(qa8[m], kb8[n], s[m][n], 0, 0, 0);
        }

    // ---- scale + bias/mask table; softmax rows in C/D layout ----
    #pragma unroll
    for (int m = 0; m < 4; ++m)
        #pragma unroll
        for (int n = 0; n < 4; ++n) {
            #pragma unroll
            for (int ii = 0; ii < 4; ++ii) {
                int i = 16 * m + 4 * g + ii, j = 16 * n + c;
                s[m][n][ii] = s[m][n][ii] * 0.17677669529663687f + tb[i * 64 + j];
            }
        }
    float inv[4][4];
    #pragma unroll
    for (int m = 0; m < 4; ++m) {
        #pragma unroll
        for (int ii = 0; ii < 4; ++ii) {
            float mx = fmaxf(fmaxf(s[m][0][ii], s[m][1][ii]), fmaxf(s[m][2][ii], s[m][3][ii]));
            #pragma unroll
            for (int o = 1; o < 16; o <<= 1) mx = fmaxf(mx, __shfl_xor(mx, o));
            float sm = 0.f;
            #pragma unroll
            for (int n = 0; n < 4; ++n) {
                float p = __expf(s[m][n][ii] - mx);
                s[m][n][ii] = p; sm += p;
            }
            #pragma unroll
            for (int o = 1; o < 16; o <<= 1) sm += __shfl_xor(sm, o);
            inv[m][ii] = 1.f / sm;
        }
    }

    // ---- P -> LDS: packed b64 writes at permuted cols phys(16n+c)=4c+n ----
    #pragma unroll
    for (int m = 0; m < 4; ++m)
        #pragma unroll
        for (int ii = 0; ii < 4; ++ii) {
            int r = 16 * m + 4 * g + ii;
            u16x4 pk;
            #pragma unroll
            for (int n = 0; n < 4; ++n) pk[n] = f2bf(s[m][n][ii]);
            *(u16x4*)&Plds[w][r][4 * c] = pk;
        }

    __syncthreads();

    // ---- O = P.V : 2 bf16 k-steps over 64 phys slots ----
    f32x4 o2[4][2];
    #pragma unroll
    for (int m = 0; m < 4; ++m)
        #pragma unroll
        for (int n = 0; n < 2; ++n) o2[m][n] = (f32x4){0.f, 0.f, 0.f, 0.f};
    #pragma unroll
    for (int ks = 0; ks < 2; ++ks) {
        bf16x8 pa[4], vb[2];
        #pragma unroll
        for (int m = 0; m < 4; ++m)
            pa[m] = *(const bf16x8*)&Plds[w][c + 16 * m][32 * ks + 8 * g];
        #pragma unroll
        for (int n = 0; n < 2; ++n)
            vb[n] = *(const bf16x8*)&Vlds[w][c + 16 * n][32 * ks + 8 * g];
        #pragma unroll
        for (int m = 0; m < 4; ++m)
            #pragma unroll
            for (int n = 0; n < 2; ++n)
                o2[m][n] = __builtin_amdgcn_mfma_f32_16x16x32_bf16(pa[m], vb[n], o2[m][n], 0, 0, 0);
    }

    // ---- store O rows < 49 (fp8), scaled by 1/rowsum ----
    #pragma unroll
    for (int m = 0; m < 4; ++m)
        #pragma unroll
        for (int ii = 0; ii < 4; ++ii) {
            int i = 16 * m + 4 * g + ii;
            if (i < 49) {
                unsigned char* orow = aout8 + ((long)lw * 49 + i) * 384 + h * 32;
                #pragma unroll
                for (int n = 0; n < 2; ++n)
                    orow[c + 16 * n] = f2fp8(o2[m][n][ii] * inv[m][ii]);
            }
        }
}

// ---------------- fp8 MFMA GEMM: 256x128 tile, BK=128, 8 waves (R21 verified) ----------------
// A[M,K] fp8 rm, Bt[N,K] fp8 rm. LDS 48 KB (2 blocks/CU). 3-bit swizzle: LDS chunk p
// of row r holds global chunk p^(r&7); store lchk=(lane&7)^(lane>>3); read
// chunk=(2kk+(g>>1))^(r&7) -> 2-way (free, m136).
// EPI: 0 = bf16 out (proj), 1 = fp8 out + rcp-GELU (fc1), 2 = fp8 out (qkv),
//      3 = f32 out + bf16 residual (fc2)
template<int EPI>
__global__ __launch_bounds__(512) void k_gemm8(
    const unsigned char* __restrict__ A,
    const unsigned char* __restrict__ Bt,
    const float* __restrict__ bias,
    unsigned short* outb16, unsigned char* outb8, float* outf,
    const unsigned short* __restrict__ resb,
    int N, int K, int m_base)
{
    __shared__ unsigned char As[256][128];   // 32 KB
    __shared__ unsigned char Bs[128][128];   // 16 KB
    int nwg = gridDim.x * gridDim.y;
    int bid = blockIdx.y * gridDim.x + blockIdx.x;
    int qq = nwg >> 3, rr = nwg & 7;
    int xcd = bid & 7, idx = bid >> 3;
    int swz = (xcd < rr) ? (xcd * (qq + 1) + idx) : (rr * (qq + 1) + (xcd - rr) * qq + idx);
    int m0 = (swz / gridDim.x) << 8;
    int n0 = (swz % gridDim.x) << 7;

    int tid = threadIdx.x, wid = tid >> 6, lane = tid & 63;
    int wr = wid >> 1, wc = wid & 1;      // 4M x 2N waves, 64x64 out each
    f32x4 acc[4][4];
    #pragma unroll
    for (int i = 0; i < 4; ++i)
        #pragma unroll
        for (int j = 0; j < 4; ++j)
            acc[i][j] = (f32x4){0.f, 0.f, 0.f, 0.f};

    // staging: 8 rows per gload_lds issue (128 B/row, 8 lanes/row).
    int lrow = lane >> 3;                  // 0..7
    int lchk = (lane & 7) ^ lrow;          // swizzled source chunk (3-bit, invariant)
    const unsigned char* Ag = A  + (long)(m0 + wid * 32 + lrow) * K + lchk * 16;
    const unsigned char* Bg = Bt + (long)(n0 + wid * 16 + lrow) * K + lchk * 16;

    for (int k0 = 0; k0 < K; k0 += 128) {
        #pragma unroll
        for (int c = 0; c < 4; ++c)
            __builtin_amdgcn_global_load_lds(
                (const __attribute__((address_space(1))) void*)(Ag + k0 + (long)c * 8 * K),
                (__attribute__((address_space(3))) void*)(&As[wid * 32 + c * 8][0]), 16, 0, 0);
        #pragma unroll
        for (int c = 0; c < 2; ++c)
            __builtin_amdgcn_global_load_lds(
                (const __attribute__((address_space(1))) void*)(Bg + k0 + (long)c * 8 * K),
                (__attribute__((address_space(3))) void*)(&Bs[wid * 16 + c * 8][0]), 16, 0, 0);
        __syncthreads();
        #pragma unroll
        for (int kk = 0; kk < 4; ++kk) {
            long long af[4], bfr[4];
            int g = lane >> 4;
            #pragma unroll
            for (int mi = 0; mi < 4; ++mi) {
                int r = wr * 64 + mi * 16 + (lane & 15);
                int chunk = (2 * kk + (g >> 1)) ^ (r & 7);
                af[mi] = *reinterpret_cast<const long long*>(&As[r][chunk * 16 + (g & 1) * 8]);
            }
            #pragma unroll
            for (int ni = 0; ni < 4; ++ni) {
                int r = wc * 64 + ni * 16 + (lane & 15);
                int chunk = (2 * kk + (g >> 1)) ^ (r & 7);
                bfr[ni] = *reinterpret_cast<const long long*>(&Bs[r][chunk * 16 + (g & 1) * 8]);
            }
            #pragma unroll
            for (int mi = 0; mi < 4; ++mi)
                #pragma unroll
                for (int ni = 0; ni < 4; ++ni)
                    acc[mi][ni] = __builtin_amdgcn_mfma_f32_16x16x32_fp8_fp8(
                        af[mi], bfr[ni], acc[mi][ni], 0, 0, 0);
        }
        __syncthreads();
    }

    #pragma unroll
    for (int mi = 0; mi < 4; ++mi) {
        #pragma unroll
        for (int ni = 0; ni < 4; ++ni) {
            int col = n0 + wc * 64 + ni * 16 + (lane & 15);
            float bv = bias[col];
            #pragma unroll
            for (int i = 0; i < 4; ++i) {
                int row = m0 + wr * 64 + mi * 16 + (lane >> 4) * 4 + i;
                float v = acc[mi][ni][i] + bv;
                if constexpr (EPI == 0) {
                    outb16[(long)row * N + col] = f2bf(v);
                } else if constexpr (EPI == 1) {
                    // sigmoid-form GELU with HW rcp (no IEEE div)
                    float e = __expf(-(1.5957691f * v + 0.0713548f * v * v * v));
                    float gv = v * __builtin_amdgcn_rcpf(1.f + e);
                    outb8[(long)row * N + col] = f2fp8(gv);
                } else if constexpr (EPI == 2) {
                    outb8[(long)row * N + col] = f2fp8(v);
                } else {
                    long oidx = (long)(m_base + row) * 384 + col;
                    outf[oidx] = v + bf2f(resb[oidx]);
                }
            }
        }
    }
}

extern "C" void kernel_launch(void* const* d_in, const int* in_sizes, int n_in,
                              void* d_out, int out_size, void* d_ws, size_t ws_size,
                              hipStream_t stream) {
    (void)in_sizes; (void)n_in; (void)out_size;
    const float* x     = (const float*)d_in[0];
    const float* n1g   = (const float*)d_in[1];
    const float* n1b   = (const float*)d_in[2];
    const float* qkvw  = (const float*)d_in[3];
    const float* qkvb  = (const float*)d_in[4];
    const float* rpb   = (const float*)d_in[5];
    const float* projw = (const float*)d_in[6];
    const float* projb = (const float*)d_in[7];
    const float* n2g   = (const float*)d_in[8];
    const float* n2b   = (const float*)d_in[9];
    const float* fc1w  = (const float*)d_in[10];
    const float* fc1b  = (const float*)d_in[11];
    const float* fc2w  = (const float*)d_in[12];
    const float* fc2b  = (const float*)d_in[13];
    float* out = (float*)d_out;

    const long Mtot = 200704;
    auto pad = [](size_t b) { return (b + 255) & ~(size_t)255; };
    size_t fixed = pad((size_t)1152 * 384) + pad((size_t)384 * 384)
                 + pad((size_t)1536 * 384) + pad((size_t)384 * 1536)
                 + pad((size_t)4 * 12 * 4096 * 4)
                 + pad((size_t)Mtot * 384)          // xw8 / h2 (fp8)
                 + pad((size_t)Mtot * 384 * 2)      // projout (bf16)
                 + pad((size_t)Mtot * 384 * 2);     // o1b (bf16 residual)
    int nc = 1;
    while (nc < 8) {
        size_t rows = Mtot / nc;
        if (fixed + pad(rows * 1536) + pad(rows * 384) <= ws_size) break;
        nc <<= 1;
    }
    long rows = Mtot / nc;            // rows per chunk, multiple of 256 and 49
    int  mb   = (int)(rows >> 8);     // 256-row tiles per chunk
    int  wpc  = (int)(rows / 49);     // windows per chunk (multiple of 64)

    char* ws = (char*)d_ws;
    size_t off = 0;
    auto alloc = [&](size_t bytes) { char* p = ws + off; off += (bytes + 255) & ~(size_t)255; return p; };
    unsigned char*  BtQ8 = (unsigned char*)alloc((size_t)1152 * 384);        // qkv weights fp8
    unsigned char*  BtP8 = (unsigned char*)alloc((size_t)384 * 384);         // proj weights fp8
    unsigned char*  Bt18 = (unsigned char*)alloc((size_t)1536 * 384);        // fc1 weights fp8
    unsigned char*  Bt28 = (unsigned char*)alloc((size_t)384 * 1536);        // fc2 weights fp8
    float*          tbl  = (float*)alloc((size_t)4 * 12 * 4096 * 4);
    unsigned char*  xw8  = (unsigned char*)alloc((size_t)Mtot * 384);        // fp8 xw; later fp8 h2
    unsigned short* pout = (unsigned short*)alloc((size_t)Mtot * 384 * 2);   // proj out (bf16, window order)
    unsigned short* o1b  = (unsigned short*)alloc((size_t)Mtot * 384 * 2);   // out1 = x+proj (bf16)
    unsigned char*  bufB8= (unsigned char*)alloc((size_t)rows * 1536);       // qkv fp8 (1152) / fc1 fp8 (1536)
    unsigned char*  attb8= (unsigned char*)alloc((size_t)rows * 384);        // attn-out fp8

    k_transpose8<<<dim3((1152 * 384 + 255) / 256), 256, 0, stream>>>(qkvw, BtQ8, 384, 1152);
    k_transpose8<<<dim3((384 * 384 + 255) / 256), 256, 0, stream>>>(projw, BtP8, 384, 384);
    k_transpose8<<<dim3((1536 * 384 + 255) / 256), 256, 0, stream>>>(fc1w, Bt18, 384, 1536);
    k_transpose8<<<dim3((384 * 1536 + 255) / 256), 256, 0, stream>>>(fc2w, Bt28, 1536, 384);
    k_btab<<<dim3(768), 256, 0, stream>>>(rpb, tbl);

    k_ln1<<<dim3(50176), 256, 0, stream>>>(x, n1g, n1b, xw8);

    // attention phase (all-fp8: qkv out fp8 -> fp8 QK^T attention -> fp8 attn-out)
    for (int c = 0; c < nc; ++c) {
        const unsigned char* Ax = xw8 + (size_t)c * rows * 384;
        k_gemm8<2><<<dim3(9, mb), 512, 0, stream>>>(Ax, BtQ8, qkvb, nullptr, bufB8, nullptr,
                                                    nullptr, 1152, 384, 0);
        k_attn<<<dim3(wpc * 3), 256, 0, stream>>>(bufB8, tbl, attb8, c * wpc);
        k_gemm8<0><<<dim3(3, mb), 512, 0, stream>>>(attb8, BtP8, projb,
                                                    pout + (size_t)c * rows * 384,
                                                    nullptr, nullptr, nullptr,
                                                    384, 384, 0);
    }

    // fused un-roll scatter + residual + LN2 (writes o1b bf16 and h2 fp8 into xw buffer)
    k_scln<<<dim3(50176), 256, 0, stream>>>(pout, x, n2g, n2b, o1b, xw8);

    // MLP phase: fc1 fp8 GEMM (rcp-GELU, fp8 out); fc2 fp8 GEMM (+bf16 residual -> f32 d_out)
    for (int c = 0; c < nc; ++c) {
        const unsigned char* Ah = xw8 + (size_t)c * rows * 384;
        k_gemm8<1><<<dim3(12, mb), 512, 0, stream>>>(Ah, Bt18, fc1b, nullptr, bufB8, nullptr,
                                                     nullptr, 1536, 384, 0);
        k_gemm8<3><<<dim3(3, mb), 512, 0, stream>>>(bufB8, Bt28, fc2b, nullptr, nullptr, out,
                                                    o1b, 384, 1536, (int)(c * rows));
    }
}

// Round 23
// 1216.429 us; speedup vs baseline: 1.2195x; 1.0113x over previous
//
#include <hip/hip_runtime.h>

// Swin block (all-fp8 GEMMs, bf16 residual edge): LN1(fp8) -> qkv fp8(fp8 out)
//   -> MFMA attn (fp8 QK^T, bf16 PV, fp8 out) -> proj fp8(bf16 out)
//   -> scatter+res+LN2(bf16 out1, fp8 h2) -> fc1 fp8(+sigmoid-GELU, fp8 out)
//   -> fc2 fp8(+bf16 residual -> f32 d_out)
// B=64, H=W=56, C=384, WS=7, SS=3, NH=12, hd=32, N=49, nW=64, B_=4096, M=200704
// R23: fc1 epilogue VALU cut (R22: VALUBusy 64.7%, epilogue ~2.6x the MFMA cycles).
//      GELU -> minimal sigmoid form v*rcp(1+exp2(-2.4554*v)): 4 VALU + 2 trans per
//      element vs ~10+2. Model err ~0.02 at |v|~2-3 where e4m3 quant step is ~0.06
//      on the same value -> subdominant. Everything else identical to R22.

typedef __bf16 bf16x8 __attribute__((ext_vector_type(8)));
typedef float  f32x4  __attribute__((ext_vector_type(4)));
typedef unsigned short u16x4 __attribute__((ext_vector_type(4)));

__device__ __forceinline__ unsigned short f2bf(float f) {
    unsigned int u = __builtin_bit_cast(unsigned int, f);
    u += 0x7fffu + ((u >> 16) & 1u);   // RNE
    return (unsigned short)(u >> 16);
}
__device__ __forceinline__ float bf2f(unsigned short h) {
    return __builtin_bit_cast(float, (unsigned int)h << 16);
}
__device__ __forceinline__ unsigned char f2fp8(float f) {   // e4m3, RNE (HW)
    return (unsigned char)(__builtin_amdgcn_cvt_pk_fp8_f32(f, f, 0, false) & 0xff);
}

// ---------------- weight transpose + cast: W[K,N] f32 -> Bt[N,K] fp8 e4m3 ----------------
__global__ __launch_bounds__(256) void k_transpose8(const float* __restrict__ W,
                                                    unsigned char* __restrict__ Bt,
                                                    int K, int N) {
    int idx = blockIdx.x * 256 + threadIdx.x;
    if (idx >= N * K) return;
    int n = idx / K, k = idx - n * K;
    Bt[idx] = f2fp8(W[(long)k * N + n]);
}

// ---------------- bias+mask table: tbl[mt][h][i][j], 4*12*64*64 f32 ----------------
__global__ __launch_bounds__(256) void k_btab(const float* __restrict__ rpb,
                                              float* __restrict__ tbl) {
    int idx = blockIdx.x * 256 + threadIdx.x;
    if (idx >= 4 * 12 * 4096) return;
    int j = idx & 63, i = (idx >> 6) & 63;
    int slab = idx >> 12;            // mt*12 + h
    int h = slab % 12, mt = slab / 12;
    float v;
    if (j >= 49)      v = -30000.f;
    else if (i >= 49) v = 0.f;
    else {
        int ith = i / 7, itw = i - ith * 7;
        int jth = j / 7, jtw = j - jth * 7;
        v = rpb[((ith - jth + 6) * 13 + (itw - jtw + 6)) * 12 + h];
        bool m = ((mt & 1) && ((ith < 4) != (jth < 4))) ||
                 ((mt & 2) && ((itw < 4) != (jtw < 4)));
        if (m) v -= 100.f;
    }
    tbl[idx] = v;
}

// ---------------- LN1 + cyclic shift(-3,-3) + window partition -> fp8 ----------------
__global__ __launch_bounds__(256) void k_ln1(const float* __restrict__ x,
                                             const float* __restrict__ g,
                                             const float* __restrict__ bb,
                                             unsigned char* __restrict__ xw8) {
    int wid = threadIdx.x >> 6, lane = threadIdx.x & 63;
    int tok = blockIdx.x * 4 + wid;                 // < 200704
    int t  = tok % 49; int b_ = tok / 49;
    int wi = b_ & 63;  int b  = b_ >> 6;
    int th = t / 7, tw = t - th * 7;
    int hs = (wi >> 3) * 7 + th + 3; if (hs >= 56) hs -= 56;
    int vs = (wi & 7) * 7 + tw + 3;  if (vs >= 56) vs -= 56;
    const float2* row = (const float2*)(x + ((long)b * 3136 + hs * 56 + vs) * 384);
    float2 v[3]; float s = 0.f;
    #pragma unroll
    for (int i = 0; i < 3; ++i) { v[i] = row[lane + 64 * i]; s += v[i].x + v[i].y; }
    #pragma unroll
    for (int o = 32; o; o >>= 1) s += __shfl_xor(s, o);
    float mean = s * (1.f / 384.f);
    float q = 0.f;
    #pragma unroll
    for (int i = 0; i < 3; ++i) {
        float dx = v[i].x - mean, dy = v[i].y - mean; q += dx * dx + dy * dy;
    }
    #pragma unroll
    for (int o = 32; o; o >>= 1) q += __shfl_xor(q, o);
    float inv = rsqrtf(q * (1.f / 384.f) + 1e-5f);
    unsigned char* orow = xw8 + (long)tok * 384;
    #pragma unroll
    for (int i = 0; i < 3; ++i) {
        int c = i * 128 + lane * 2;
        unsigned short p = (unsigned short)f2fp8((v[i].x - mean) * inv * g[c] + bb[c])
                         | ((unsigned short)f2fp8((v[i].y - mean) * inv * g[c + 1] + bb[c + 1]) << 8);
        *(unsigned short*)(orow + c) = p;
    }
}

// ------- fused un-roll scatter + residual + LN2: o1b = bf16(x + gather(projout)); h2 = LN2 fp8 -------
__global__ __launch_bounds__(256) void k_scln(const unsigned short* __restrict__ po,
                                              const float* __restrict__ x,
                                              const float* __restrict__ g,
                                              const float* __restrict__ bb,
                                              unsigned short* __restrict__ o1b,
                                              unsigned char* __restrict__ h2) {
    int wid = threadIdx.x >> 6, lane = threadIdx.x & 63;
    int tok = blockIdx.x * 4 + wid;                 // < 200704
    int b = tok / 3136, rem = tok - b * 3136;
    int hh = rem / 56, ww = rem - hh * 56;
    int u = (hh >= 3) ? hh - 3 : hh + 53;           // inverse roll(+3)
    int v = (ww >= 3) ? ww - 3 : ww + 53;
    int wr = u / 7, th = u - wr * 7;
    int wc = v / 7, tw = v - wc * 7;
    long src = ((long)((b << 6) + wr * 8 + wc) * 49 + th * 7 + tw) * 384;
    const unsigned int* prow = (const unsigned int*)(po + src);    // 2 bf16 / uint
    const float2* xrow = (const float2*)(x + (long)tok * 384);
    float2 o[3]; float s = 0.f;
    #pragma unroll
    for (int i = 0; i < 3; ++i) {
        unsigned int pb = prow[lane + 64 * i];
        float2 xv = xrow[lane + 64 * i];
        o[i].x = xv.x + bf2f((unsigned short)(pb & 0xffffu));
        o[i].y = xv.y + bf2f((unsigned short)(pb >> 16));
        s += o[i].x + o[i].y;
    }
    unsigned short* orow = o1b + (long)tok * 384;
    #pragma unroll
    for (int i = 0; i < 3; ++i) {
        int c = i * 128 + lane * 2;
        unsigned int p = (unsigned int)f2bf(o[i].x) | ((unsigned int)f2bf(o[i].y) << 16);
        *(unsigned int*)(orow + c) = p;
    }
    #pragma unroll
    for (int of = 32; of; of >>= 1) s += __shfl_xor(s, of);
    float mean = s * (1.f / 384.f);
    float q = 0.f;
    #pragma unroll
    for (int i = 0; i < 3; ++i) {
        float dx = o[i].x - mean, dy = o[i].y - mean; q += dx * dx + dy * dy;
    }
    #pragma unroll
    for (int of = 32; of; of >>= 1) q += __shfl_xor(q, of);
    float inv = rsqrtf(q * (1.f / 384.f) + 1e-5f);
    unsigned char* hrow = h2 + (long)tok * 384;
    #pragma unroll
    for (int i = 0; i < 3; ++i) {
        int c = i * 128 + lane * 2;
        unsigned short p = (unsigned short)f2fp8((o[i].x - mean) * inv * g[c] + bb[c])
                         | ((unsigned short)f2fp8((o[i].y - mean) * inv * g[c + 1] + bb[c + 1]) << 8);
        *(unsigned short*)(hrow + c) = p;
    }
}

// ---------------- MFMA windowed attention: 1 wave = 1 (window, head), 4 waves/block ----------------
__global__ __launch_bounds__(256) void k_attn(const unsigned char* __restrict__ qkv8,
                                              const float* __restrict__ tbl,     // [4][12][64][64]
                                              unsigned char* __restrict__ aout8, // [nwin*49,384] fp8
                                              int win_base) {
    __shared__ unsigned short Plds[4][64][72];
    __shared__ unsigned short Vlds[4][32][72];
    int tid = threadIdx.x;
    int w = tid >> 6, lane = tid & 63;
    int wg = blockIdx.x * 4 + w;
    int lw = wg / 12;                  // local window
    int h  = wg - lw * 12;             // head
    int g  = lane >> 4, c = lane & 15;
    const unsigned char* base = qkv8 + (long)lw * 49 * 1152;

    int wi = (win_base + lw) & 63;
    int mt = ((wi >> 3) == 7 ? 1 : 0) | ((wi & 7) == 7 ? 2 : 0);
    const float* tb = tbl + ((long)(mt * 12 + h) << 12);

    // ---- stage V (permuted rows) fp8->bf16 into LDS; zero-fill padding rows 49..63 ----
    #pragma unroll
    for (int it = 0; it < 4; ++it) {
        int t = it * 64 + lane;        // t < 256
        int j = t >> 2, o = t & 3;
        int pj = 4 * (j & 15) + (j >> 4);     // phys slot
        if (j < 49) {
            uint2 vv = *(const uint2*)(base + (long)j * 1152 + 768 + h * 32 + o * 8);
            Vlds[w][o * 8 + 0][pj] = f2bf(__builtin_amdgcn_cvt_f32_fp8(vv.x, 0));
            Vlds[w][o * 8 + 1][pj] = f2bf(__builtin_amdgcn_cvt_f32_fp8(vv.x, 1));
            Vlds[w][o * 8 + 2][pj] = f2bf(__builtin_amdgcn_cvt_f32_fp8(vv.x, 2));
            Vlds[w][o * 8 + 3][pj] = f2bf(__builtin_amdgcn_cvt_f32_fp8(vv.x, 3));
            Vlds[w][o * 8 + 4][pj] = f2bf(__builtin_amdgcn_cvt_f32_fp8(vv.y, 0));
            Vlds[w][o * 8 + 5][pj] = f2bf(__builtin_amdgcn_cvt_f32_fp8(vv.y, 1));
            Vlds[w][o * 8 + 6][pj] = f2bf(__builtin_amdgcn_cvt_f32_fp8(vv.y, 2));
            Vlds[w][o * 8 + 7][pj] = f2bf(__builtin_amdgcn_cvt_f32_fp8(vv.y, 3));
        } else {
            #pragma unroll
            for (int e = 0; e < 8; ++e) Vlds[w][o * 8 + e][pj] = 0;
        }
    }

    // ---- Q and K fp8 fragments straight from global (lane c: bytes 8g..8g+8 of row) ----
    long long qa8[4], kb8[4];
    #pragma unroll
    for (int m = 0; m < 4; ++m) {
        int qr = 16 * m + c; if (qr > 48) qr = 48;
        qa8[m] = *(const long long*)(base + (long)qr * 1152 + h * 32 + 8 * g);
    }
    #pragma unroll
    for (int n = 0; n < 4; ++n) {
        int jr = 16 * n + c; if (jr > 48) jr = 48;
        kb8[n] = *(const long long*)(base + (long)jr * 1152 + 384 + h * 32 + 8 * g);
    }

    // ---- S = Q.K^T : 16 fp8 MFMA, single k-step (K=hd=32) ----
    f32x4 s[4][4];
    #pragma unroll
    for (int m = 0; m < 4; ++m)
        #pragma unroll
        for (int n = 0; n < 4; ++n) {
            s[m][n] = (f32x4){0.f, 0.f, 0.f, 0.f};
            s[m][n] = __builtin_amdgcn_mfma_f32_16x16x32_fp8_fp8(qa8[m], kb8[n], s[m][n], 0, 0, 0);
        }

    // ---- scale + bias/mask table; softmax rows in C/D layout ----
    #pragma unroll
    for (int m = 0; m < 4; ++m)
        #pragma unroll
        for (int n = 0; n < 4; ++n) {
            #pragma unroll
            for (int ii = 0; ii < 4; ++ii) {
                int i = 16 * m + 4 * g + ii, j = 16 * n + c;
                s[m][n][ii] = s[m][n][ii] * 0.17677669529663687f + tb[i * 64 + j];
            }
        }
    float inv[4][4];
    #pragma unroll
    for (int m = 0; m < 4; ++m) {
        #pragma unroll
        for (int ii = 0; ii < 4; ++ii) {
            float mx = fmaxf(fmaxf(s[m][0][ii], s[m][1][ii]), fmaxf(s[m][2][ii], s[m][3][ii]));
            #pragma unroll
            for (int o = 1; o < 16; o <<= 1) mx = fmaxf(mx, __shfl_xor(mx, o));
            float sm = 0.f;
            #pragma unroll
            for (int n = 0; n < 4; ++n) {
                float p = __expf(s[m][n][ii] - mx);
                s[m][n][ii] = p; sm += p;
            }
            #pragma unroll
            for (int o = 1; o < 16; o <<= 1) sm += __shfl_xor(sm, o);
            inv[m][ii] = 1.f / sm;
        }
    }

    // ---- P -> LDS: packed b64 writes at permuted cols phys(16n+c)=4c+n ----
    #pragma unroll
    for (int m = 0; m < 4; ++m)
        #pragma unroll
        for (int ii = 0; ii < 4; ++ii) {
            int r = 16 * m + 4 * g + ii;
            u16x4 pk;
            #pragma unroll
            for (int n = 0; n < 4; ++n) pk[n] = f2bf(s[m][n][ii]);
            *(u16x4*)&Plds[w][r][4 * c] = pk;
        }

    __syncthreads();

    // ---- O = P.V : 2 bf16 k-steps over 64 phys slots ----
    f32x4 o2[4][2];
    #pragma unroll
    for (int m = 0; m < 4; ++m)
        #pragma unroll
        for (int n = 0; n < 2; ++n) o2[m][n] = (f32x4){0.f, 0.f, 0.f, 0.f};
    #pragma unroll
    for (int ks = 0; ks < 2; ++ks) {
        bf16x8 pa[4], vb[2];
        #pragma unroll
        for (int m = 0; m < 4; ++m)
            pa[m] = *(const bf16x8*)&Plds[w][c + 16 * m][32 * ks + 8 * g];
        #pragma unroll
        for (int n = 0; n < 2; ++n)
            vb[n] = *(const bf16x8*)&Vlds[w][c + 16 * n][32 * ks + 8 * g];
        #pragma unroll
        for (int m = 0; m < 4; ++m)
            #pragma unroll
            for (int n = 0; n < 2; ++n)
                o2[m][n] = __builtin_amdgcn_mfma_f32_16x16x32_bf16(pa[m], vb[n], o2[m][n], 0, 0, 0);
    }

    // ---- store O rows < 49 (fp8), scaled by 1/rowsum ----
    #pragma unroll
    for (int m = 0; m < 4; ++m)
        #pragma unroll
        for (int ii = 0; ii < 4; ++ii) {
            int i = 16 * m + 4 * g + ii;
            if (i < 49) {
                unsigned char* orow = aout8 + ((long)lw * 49 + i) * 384 + h * 32;
                #pragma unroll
                for (int n = 0; n < 2; ++n)
                    orow[c + 16 * n] = f2fp8(o2[m][n][ii] * inv[m][ii]);
            }
        }
}

// ---------------- fp8 MFMA GEMM: 256x128 tile, BK=128, 8 waves (R21 verified) ----------------
// A[M,K] fp8 rm, Bt[N,K] fp8 rm. LDS 48 KB (2 blocks/CU). 3-bit swizzle: LDS chunk p
// of row r holds global chunk p^(r&7); store lchk=(lane&7)^(lane>>3); read
// chunk=(2kk+(g>>1))^(r&7) -> 2-way (free, m136).
// EPI: 0 = bf16 out (proj), 1 = fp8 out + sigmoid-GELU (fc1), 2 = fp8 out (qkv),
//      3 = f32 out + bf16 residual (fc2)
template<int EPI>
__global__ __launch_bounds__(512) void k_gemm8(
    const unsigned char* __restrict__ A,
    const unsigned char* __restrict__ Bt,
    const float* __restrict__ bias,
    unsigned short* outb16, unsigned char* outb8, float* outf,
    const unsigned short* __restrict__ resb,
    int N, int K, int m_base)
{
    __shared__ unsigned char As[256][128];   // 32 KB
    __shared__ unsigned char Bs[128][128];   // 16 KB
    int nwg = gridDim.x * gridDim.y;
    int bid = blockIdx.y * gridDim.x + blockIdx.x;
    int qq = nwg >> 3, rr = nwg & 7;
    int xcd = bid & 7, idx = bid >> 3;
    int swz = (xcd < rr) ? (xcd * (qq + 1) + idx) : (rr * (qq + 1) + (xcd - rr) * qq + idx);
    int m0 = (swz / gridDim.x) << 8;
    int n0 = (swz % gridDim.x) << 7;

    int tid = threadIdx.x, wid = tid >> 6, lane = tid & 63;
    int wr = wid >> 1, wc = wid & 1;      // 4M x 2N waves, 64x64 out each
    f32x4 acc[4][4];
    #pragma unroll
    for (int i = 0; i < 4; ++i)
        #pragma unroll
        for (int j = 0; j < 4; ++j)
            acc[i][j] = (f32x4){0.f, 0.f, 0.f, 0.f};

    // staging: 8 rows per gload_lds issue (128 B/row, 8 lanes/row).
    int lrow = lane >> 3;                  // 0..7
    int lchk = (lane & 7) ^ lrow;          // swizzled source chunk (3-bit, invariant)
    const unsigned char* Ag = A  + (long)(m0 + wid * 32 + lrow) * K + lchk * 16;
    const unsigned char* Bg = Bt + (long)(n0 + wid * 16 + lrow) * K + lchk * 16;

    for (int k0 = 0; k0 < K; k0 += 128) {
        #pragma unroll
        for (int c = 0; c < 4; ++c)
            __builtin_amdgcn_global_load_lds(
                (const __attribute__((address_space(1))) void*)(Ag + k0 + (long)c * 8 * K),
                (__attribute__((address_space(3))) void*)(&As[wid * 32 + c * 8][0]), 16, 0, 0);
        #pragma unroll
        for (int c = 0; c < 2; ++c)
            __builtin_amdgcn_global_load_lds(
                (const __attribute__((address_space(1))) void*)(Bg + k0 + (long)c * 8 * K),
                (__attribute__((address_space(3))) void*)(&Bs[wid * 16 + c * 8][0]), 16, 0, 0);
        __syncthreads();
        #pragma unroll
        for (int kk = 0; kk < 4; ++kk) {
            long long af[4], bfr[4];
            int g = lane >> 4;
            #pragma unroll
            for (int mi = 0; mi < 4; ++mi) {
                int r = wr * 64 + mi * 16 + (lane & 15);
                int chunk = (2 * kk + (g >> 1)) ^ (r & 7);
                af[mi] = *reinterpret_cast<const long long*>(&As[r][chunk * 16 + (g & 1) * 8]);
            }
            #pragma unroll
            for (int ni = 0; ni < 4; ++ni) {
                int r = wc * 64 + ni * 16 + (lane & 15);
                int chunk = (2 * kk + (g >> 1)) ^ (r & 7);
                bfr[ni] = *reinterpret_cast<const long long*>(&Bs[r][chunk * 16 + (g & 1) * 8]);
            }
            #pragma unroll
            for (int mi = 0; mi < 4; ++mi)
                #pragma unroll
                for (int ni = 0; ni < 4; ++ni)
                    acc[mi][ni] = __builtin_amdgcn_mfma_f32_16x16x32_fp8_fp8(
                        af[mi], bfr[ni], acc[mi][ni], 0, 0, 0);
        }
        __syncthreads();
    }

    #pragma unroll
    for (int mi = 0; mi < 4; ++mi) {
        #pragma unroll
        for (int ni = 0; ni < 4; ++ni) {
            int col = n0 + wc * 64 + ni * 16 + (lane & 15);
            float bv = bias[col];
            #pragma unroll
            for (int i = 0; i < 4; ++i) {
                int row = m0 + wr * 64 + mi * 16 + (lane >> 4) * 4 + i;
                float v = acc[mi][ni][i] + bv;
                if constexpr (EPI == 0) {
                    outb16[(long)row * N + col] = f2bf(v);
                } else if constexpr (EPI == 1) {
                    // minimal sigmoid-GELU: v * rcp(1 + exp2(-2.4554*v))
                    // (1.702/ln2 = 2.4554; err ~0.02 << e4m3 quant at same magnitude)
                    float e = __builtin_amdgcn_exp2f(-2.4554085f * v);
                    float gv = v * __builtin_amdgcn_rcpf(1.f + e);
                    outb8[(long)row * N + col] = f2fp8(gv);
                } else if constexpr (EPI == 2) {
                    outb8[(long)row * N + col] = f2fp8(v);
                } else {
                    long oidx = (long)(m_base + row) * 384 + col;
                    outf[oidx] = v + bf2f(resb[oidx]);
                }
            }
        }
    }
}

extern "C" void kernel_launch(void* const* d_in, const int* in_sizes, int n_in,
                              void* d_out, int out_size, void* d_ws, size_t ws_size,
                              hipStream_t stream) {
    (void)in_sizes; (void)n_in; (void)out_size;
    const float* x     = (const float*)d_in[0];
    const float* n1g   = (const float*)d_in[1];
    const float* n1b   = (const float*)d_in[2];
    const float* qkvw  = (const float*)d_in[3];
    const float* qkvb  = (const float*)d_in[4];
    const float* rpb   = (const float*)d_in[5];
    const float* projw = (const float*)d_in[6];
    const float* projb = (const float*)d_in[7];
    const float* n2g   = (const float*)d_in[8];
    const float* n2b   = (const float*)d_in[9];
    const float* fc1w  = (const float*)d_in[10];
    const float* fc1b  = (const float*)d_in[11];
    const float* fc2w  = (const float*)d_in[12];
    const float* fc2b  = (const float*)d_in[13];
    float* out = (float*)d_out;

    const long Mtot = 200704;
    auto pad = [](size_t b) { return (b + 255) & ~(size_t)255; };
    size_t fixed = pad((size_t)1152 * 384) + pad((size_t)384 * 384)
                 + pad((size_t)1536 * 384) + pad((size_t)384 * 1536)
                 + pad((size_t)4 * 12 * 4096 * 4)
                 + pad((size_t)Mtot * 384)          // xw8 / h2 (fp8)
                 + pad((size_t)Mtot * 384 * 2)      // projout (bf16)
                 + pad((size_t)Mtot * 384 * 2);     // o1b (bf16 residual)
    int nc = 1;
    while (nc < 8) {
        size_t rows = Mtot / nc;
        if (fixed + pad(rows * 1536) + pad(rows * 384) <= ws_size) break;
        nc <<= 1;
    }
    long rows = Mtot / nc;            // rows per chunk, multiple of 256 and 49
    int  mb   = (int)(rows >> 8);     // 256-row tiles per chunk
    int  wpc  = (int)(rows / 49);     // windows per chunk (multiple of 64)

    char* ws = (char*)d_ws;
    size_t off = 0;
    auto alloc = [&](size_t bytes) { char* p = ws + off; off += (bytes + 255) & ~(size_t)255; return p; };
    unsigned char*  BtQ8 = (unsigned char*)alloc((size_t)1152 * 384);        // qkv weights fp8
    unsigned char*  BtP8 = (unsigned char*)alloc((size_t)384 * 384);         // proj weights fp8
    unsigned char*  Bt18 = (unsigned char*)alloc((size_t)1536 * 384);        // fc1 weights fp8
    unsigned char*  Bt28 = (unsigned char*)alloc((size_t)384 * 1536);        // fc2 weights fp8
    float*          tbl  = (float*)alloc((size_t)4 * 12 * 4096 * 4);
    unsigned char*  xw8  = (unsigned char*)alloc((size_t)Mtot * 384);        // fp8 xw; later fp8 h2
    unsigned short* pout = (unsigned short*)alloc((size_t)Mtot * 384 * 2);   // proj out (bf16, window order)
    unsigned short* o1b  = (unsigned short*)alloc((size_t)Mtot * 384 * 2);   // out1 = x+proj (bf16)
    unsigned char*  bufB8= (unsigned char*)alloc((size_t)rows * 1536);       // qkv fp8 (1152) / fc1 fp8 (1536)
    unsigned char*  attb8= (unsigned char*)alloc((size_t)rows * 384);        // attn-out fp8

    k_transpose8<<<dim3((1152 * 384 + 255) / 256), 256, 0, stream>>>(qkvw, BtQ8, 384, 1152);
    k_transpose8<<<dim3((384 * 384 + 255) / 256), 256, 0, stream>>>(projw, BtP8, 384, 384);
    k_transpose8<<<dim3((1536 * 384 + 255) / 256), 256, 0, stream>>>(fc1w, Bt18, 384, 1536);
    k_transpose8<<<dim3((384 * 1536 + 255) / 256), 256, 0, stream>>>(fc2w, Bt28, 1536, 384);
    k_btab<<<dim3(768), 256, 0, stream>>>(rpb, tbl);

    k_ln1<<<dim3(50176), 256, 0, stream>>>(x, n1g, n1b, xw8);

    // attention phase (all-fp8: qkv out fp8 -> fp8 QK^T attention -> fp8 attn-out)
    for (int c = 0; c < nc; ++c) {
        const unsigned char* Ax = xw8 + (size_t)c * rows * 384;
        k_gemm8<2><<<dim3(9, mb), 512, 0, stream>>>(Ax, BtQ8, qkvb, nullptr, bufB8, nullptr,
                                                    nullptr, 1152, 384, 0);
        k_attn<<<dim3(wpc * 3), 256, 0, stream>>>(bufB8, tbl, attb8, c * wpc);
        k_gemm8<0><<<dim3(3, mb), 512, 0, stream>>>(attb8, BtP8, projb,
                                                    pout + (size_t)c * rows * 384,
                                                    nullptr, nullptr, nullptr,
                                                    384, 384, 0);
    }

    // fused un-roll scatter + residual + LN2 (writes o1b bf16 and h2 fp8 into xw buffer)
    k_scln<<<dim3(50176), 256, 0, stream>>>(pout, x, n2g, n2b, o1b, xw8);

    // MLP phase: fc1 fp8 GEMM (sigmoid-GELU, fp8 out); fc2 fp8 GEMM (+bf16 residual -> f32 d_out)
    for (int c = 0; c < nc; ++c) {
        const unsigned char* Ah = xw8 + (size_t)c * rows * 384;
        k_gemm8<1><<<dim3(12, mb), 512, 0, stream>>>(Ah, Bt18, fc1b, nullptr, bufB8, nullptr,
                                                     nullptr, 1536, 384, 0);
        k_gemm8<3><<<dim3(3, mb), 512, 0, stream>>>(bufB8, Bt28, fc2b, nullptr, nullptr, out,
                                                    o1b, 384, 1536, (int)(c * rows));
    }
}